// Round 11
// baseline (157.813 us; speedup 1.0000x reference)
//
#include <hip/hip_runtime.h>
#include <hip/hip_bf16.h>

// ChannelDeAttention: B=64,S=512,C=256,H=128,P=512
// bf16 MFMA (16x16x32), fp32 accum. 6 launches. XOR-swizzled LDS.
// R11: all GEMMs 4-wave 128x128 single-buf 32KB (3 blocks/CU, m97 structure),
// swapped-operand MFMA for packed 8B/16B stores. WVO fusion kept.

typedef __attribute__((ext_vector_type(8))) short bf16x8;
typedef __attribute__((ext_vector_type(4))) float f32x4;
typedef __attribute__((ext_vector_type(8))) unsigned short ushort8;

typedef __attribute__((address_space(1))) void* as1vp;
typedef __attribute__((address_space(3))) void* as3vp;

__device__ __forceinline__ void gl2lds16(const void* g, void* l) {
  __builtin_amdgcn_global_load_lds((as1vp)(void*)g, (as3vp)l, 16, 0, 0);
}

__device__ __forceinline__ float bf2f(unsigned short u) {
  union { unsigned int i; float f; } v; v.i = ((unsigned int)u) << 16; return v.f;
}
__device__ __forceinline__ unsigned short f2bf(float f) {
  union { float f; unsigned int i; } v; v.f = f;
  unsigned int r = v.i + 0x7FFFu + ((v.i >> 16) & 1u);
  return (unsigned short)(r >> 16);
}
__device__ __forceinline__ unsigned long long pack4bf(float a, float b, float c, float d) {
  return (unsigned long long)f2bf(a) | ((unsigned long long)f2bf(b) << 16) |
         ((unsigned long long)f2bf(c) << 32) | ((unsigned long long)f2bf(d) << 48);
}

// ------- transposes (x + 5 weight mats) + plain wv cast, one launch -----------------
__global__ void __launch_bounds__(256) tcast_all(
    const float* __restrict__ x,
    const float* __restrict__ wq1, const float* __restrict__ wk1,
    const float* __restrict__ wq2, const float* __restrict__ wk2,
    const float* __restrict__ wq3, const float* __restrict__ wk3,
    const float* __restrict__ wv, const float* __restrict__ wo,
    unsigned short* __restrict__ XT,
    unsigned short* __restrict__ W1, unsigned short* __restrict__ W2,
    unsigned short* __restrict__ W3, unsigned short* __restrict__ WVNT,
    unsigned short* __restrict__ WOT) {
  const int bid = blockIdx.x;
  const int t = threadIdx.x;
  if (bid >= 2168) {  // plain-cast wv to bf16 row-major (coalesced)
    long i0 = (long)(bid - 2168) * 2048 + t * 8;
    f32x4 a = *(const f32x4*)(wv + i0);
    f32x4 b = *(const f32x4*)(wv + i0 + 4);
    ushort8 o;
#pragma unroll
    for (int j = 0; j < 4; ++j) { o[j] = f2bf(a[j]); o[4 + j] = f2bf(b[j]); }
    *(ushort8*)(WVNT + i0) = o;
    return;
  }
  __shared__ float lds[64][68];
  const float* S; unsigned short* D; int R, Cc, r0, c0, rowoff = 0;
  if (bid < 2048) {
    int bz = bid >> 5, i = bid & 31;
    S = x + (long)bz * 131072; D = XT + (long)bz * 131072;
    R = 512; Cc = 256; r0 = (i & 7) * 64; c0 = (i >> 3) * 64;
  } else {
    int wb = bid - 2048;
    if (wb < 32) {
      int m = wb >> 4, i = wb & 15;
      S = m ? wk1 : wq1; D = W1; R = 512; Cc = 128;
      r0 = (i & 7) * 64; c0 = (i >> 3) * 64; rowoff = m * 128;
    } else if (wb < 48) {
      int m = (wb - 32) >> 3, i = (wb - 32) & 7;
      S = m ? wk2 : wq2; D = W2; R = 256; Cc = 128;
      r0 = (i & 3) * 64; c0 = (i >> 2) * 64; rowoff = m * 128;
    } else if (wb < 56) {
      int m = (wb - 48) >> 2, i = (wb - 48) & 3;
      S = m ? wk3 : wq3; D = W3; R = 128; Cc = 128;
      r0 = (i & 1) * 64; c0 = (i >> 1) * 64; rowoff = m * 128;
    } else {
      int i = wb - 56; S = wo; D = WOT; R = 512; Cc = 512;
      r0 = (i & 7) * 64; c0 = (i >> 3) * 64;
    }
  }
  {
    const int row = t >> 2, cq = (t & 3) * 16;
    const float* Sp = S + (long)(r0 + row) * Cc + c0 + cq;
#pragma unroll
    for (int j = 0; j < 4; ++j)
      *(f32x4*)&lds[row][cq + j * 4] = *(const f32x4*)(Sp + j * 4);
  }
  __syncthreads();
  {
    const int rq = (t & 15) * 4, ccb = t >> 4;
#pragma unroll
    for (int j = 0; j < 4; ++j) {
      int cc = ccb + j * 16;
      *(unsigned long long*)(D + (long)(c0 + cc + rowoff) * R + r0 + rq) =
          pack4bf(lds[rq][cc], lds[rq + 1][cc], lds[rq + 2][cc], lds[rq + 3][cc]);
    }
  }
}

// ------- fused Q/K projections + WVOT tiles + BVO, one launch -----------------------
// 4 waves, 128x128, single-buf 32KB, swapped mfma, packed stores.
// grid (2,2,453): z<448 proj; z in [448,452) WVOT; z==452 BVO.
__global__ void __launch_bounds__(256) proj4(
    const unsigned short* __restrict__ XT,
    const unsigned short* __restrict__ W1, const unsigned short* __restrict__ W2,
    const unsigned short* __restrict__ W3,
    const unsigned short* __restrict__ WOT, const unsigned short* __restrict__ WVNT,
    unsigned short* __restrict__ WVOT, float* __restrict__ BVO,
    const float* __restrict__ bv,
    unsigned short* __restrict__ Q1, unsigned short* __restrict__ Q2,
    unsigned short* __restrict__ Q3,
    const float* __restrict__ bq1, const float* __restrict__ bk1,
    const float* __restrict__ bq2, const float* __restrict__ bk2,
    const float* __restrict__ bq3, const float* __restrict__ bk3) {
  extern __shared__ char smem[];  // A [128][64]sw 16K + B [128][64]sw 16K
  const int z = blockIdx.z;
  const int t = threadIdx.x, lane = t & 63, wid = t >> 6;
  const int wm = (wid >> 1) * 64, wn = (wid & 1) * 64;
  const int srow = t >> 3, ssl = t & 7;

  if (z == 452) {  // ---- BVO[p] = sum_s bv[s]*WOT[p][s]; 4 blocks x 4 waves x 32 p
    int p0 = (blockIdx.y * 2 + blockIdx.x) * 128 + wid * 32;
    f32x4 b0 = *(const f32x4*)(bv + lane * 8);
    f32x4 b1 = *(const f32x4*)(bv + lane * 8 + 4);
#pragma unroll
    for (int i = 0; i < 32; ++i) {
      int p = p0 + i;
      bf16x8 wrow = *(const bf16x8*)(WOT + (long)p * 512 + lane * 8);
      float s = 0.0f;
#pragma unroll
      for (int j = 0; j < 4; ++j) {
        s += b0[j] * bf2f((unsigned short)wrow[j]);
        s += b1[j] * bf2f((unsigned short)wrow[4 + j]);
      }
#pragma unroll
      for (int off = 1; off < 64; off <<= 1) s += __shfl_xor(s, off, 64);
      if (lane == 0) BVO[p] = s;
    }
    return;
  }

  // select operands
  const unsigned short* Ab;
  const unsigned short* Bb;
  int K, lda, ldb;
  if (z >= 448) {  // WVOT tile
    int idx = (z - 448) * 4 + blockIdx.y * 2 + blockIdx.x;
    Ab = WOT + (long)(idx >> 2) * 128 * 512;
    Bb = WVNT + (long)(idx & 3) * 128 * 512;
    K = 512; lda = 512; ldb = 512;
  } else {
    const unsigned short* Bw;
    if (z < 64) {
      K = 512; Bw = W1; Ab = XT + (long)z * 131072;
    } else if (z < 192) {
      int u = z - 64; K = 256; Bw = W2;
      Ab = XT + (long)(u >> 1) * 131072 + (u & 1) * 256;
    } else {
      int u = z - 192; K = 128; Bw = W3;
      Ab = XT + (long)(u >> 2) * 131072 + (u & 3) * 128;
    }
    Ab += (long)blockIdx.y * 128 * 512;
    Bb = Bw + (long)blockIdx.x * 128 * K;
    lda = 512; ldb = K;
  }

  f32x4 acc[4][4] = {};
  for (int k0 = 0; k0 < K; k0 += 64) {
#pragma unroll
    for (int i = 0; i < 4; ++i) {
      int row = i * 32 + srow;
      int scol = (ssl ^ (row & 7)) * 8;
      gl2lds16(Ab + (long)row * lda + k0 + scol, smem + i * 4096 + t * 16);
      gl2lds16(Bb + (long)row * ldb + k0 + scol, smem + 16384 + i * 4096 + t * 16);
    }
    __syncthreads();
#pragma unroll
    for (int kk = 0; kk < 2; ++kk) {
      const int slot = kk * 4 + (lane >> 4);
      bf16x8 af[4], bfr[4];
#pragma unroll
      for (int mi = 0; mi < 4; ++mi) {
        int row = wm + mi * 16 + (lane & 15);
        af[mi] = *(const bf16x8*)(smem + row * 128 + 16 * (slot ^ (row & 7)));
      }
#pragma unroll
      for (int ni = 0; ni < 4; ++ni) {
        int row = wn + ni * 16 + (lane & 15);
        bfr[ni] = *(const bf16x8*)(smem + 16384 + row * 128 + 16 * (slot ^ (row & 7)));
      }
      // swapped operands: lane holds 4 consecutive n (cols) per fragment
#pragma unroll
      for (int mi = 0; mi < 4; ++mi)
#pragma unroll
        for (int ni = 0; ni < 4; ++ni)
          acc[mi][ni] = __builtin_amdgcn_mfma_f32_16x16x32_bf16(bfr[ni], af[mi], acc[mi][ni], 0, 0, 0);
    }
    __syncthreads();
  }

  if (z >= 448) {  // WVOT store
    int idx = (z - 448) * 4 + blockIdx.y * 2 + blockIdx.x;
    int m0 = (idx >> 2) * 128, n0 = (idx & 3) * 128;
#pragma unroll
    for (int mi = 0; mi < 4; ++mi) {
      int rowm = m0 + wm + mi * 16 + (lane & 15);
#pragma unroll
      for (int ni = 0; ni < 4; ++ni) {
        int ncb = n0 + wn + ni * 16 + (lane >> 4) * 4;
        *(unsigned long long*)(WVOT + (long)rowm * 512 + ncb) =
            pack4bf(acc[mi][ni][0], acc[mi][ni][1], acc[mi][ni][2], acc[mi][ni][3]);
      }
    }
    return;
  }

  // proj store: O[channel][qk-col], col-bias
  unsigned short* O; const float *bq, *bk;
  if (z < 64) { O = Q1 + (long)z * 65536; bq = bq1; bk = bk1; }
  else if (z < 192) { O = Q2 + (long)(z - 64) * 65536; bq = bq2; bk = bk2; }
  else { O = Q3 + (long)(z - 192) * 65536; bq = bq3; bk = bk3; }
  const int n0 = blockIdx.x * 128, m0 = blockIdx.y * 128;
  const float* bias = (n0 == 0) ? bq : bk;
#pragma unroll
  for (int mi = 0; mi < 4; ++mi) {
    int rowm = m0 + wm + mi * 16 + (lane & 15);
#pragma unroll
    for (int ni = 0; ni < 4; ++ni) {
      int ncb = wn + ni * 16 + (lane >> 4) * 4;  // 0..127 within q/k half
      *(unsigned long long*)(O + (long)rowm * 256 + n0 + ncb) =
          pack4bf(acc[mi][ni][0] + bias[ncb], acc[mi][ni][1] + bias[ncb + 1],
                  acc[mi][ni][2] + bias[ncb + 2], acc[mi][ni][3] + bias[ncb + 3]);
    }
  }
}

// ------- pass A: scales 2+3 scores + softmax + sub-batch mean (unchanged) -----------
__global__ void __launch_bounds__(256) scores_mean(
    const unsigned short* __restrict__ QK2, const unsigned short* __restrict__ QK3,
    unsigned short* __restrict__ A2P, unsigned short* __restrict__ A3P) {
  __shared__ unsigned short Qs[64 * 64];
  __shared__ unsigned short Ks[256 * 64];
  const int bid = blockIdx.x;
  const unsigned short* QK; unsigned short* Aout; int NS, b, m0idx;
  if (bid < 256) { NS = 4; b = bid >> 2; m0idx = bid & 3; QK = QK3; Aout = A3P; }
  else { int u = bid - 256; NS = 2; b = u >> 2; m0idx = u & 3; QK = QK2; Aout = A2P; }
  const int m0 = m0idx * 64;
  const int t = threadIdx.x, lane = t & 63, w = t >> 6;
  const int r8 = t >> 3, sl = t & 7;
  const float sc = 0.088388347648318447f;
  const float invNS = 1.0f / NS;
  f32x4 avg[16] = {};
  for (int h = 0; h < NS; ++h) {
    const unsigned short* base = QK + ((long)(b * NS + h) << 16);
    f32x4 acc[16] = {};
    for (int kc = 0; kc < 2; ++kc) {
#pragma unroll
      for (int i = 0; i < 2; ++i) {
        int row = i * 32 + r8;
        gl2lds16(base + (long)(m0 + row) * 256 + kc * 64 + (sl ^ (row & 7)) * 8,
                 (char*)Qs + i * 4096 + t * 16);
      }
#pragma unroll
      for (int i = 0; i < 8; ++i) {
        int row = i * 32 + r8;
        gl2lds16(base + (long)row * 256 + 128 + kc * 64 + (sl ^ (row & 7)) * 8,
                 (char*)Ks + i * 4096 + t * 16);
      }
      __syncthreads();
#pragma unroll
      for (int kk = 0; kk < 2; ++kk) {
        const int qrow = w * 16 + (lane & 15);
        const int slot = kk * 4 + (lane >> 4);
        bf16x8 qf = *(const bf16x8*)((char*)Qs + qrow * 128 + 16 * (slot ^ (qrow & 7)));
#pragma unroll
        for (int ni = 0; ni < 16; ++ni) {
          int krow = ni * 16 + (lane & 15);
          bf16x8 kf = *(const bf16x8*)((char*)Ks + krow * 128 + 16 * (slot ^ (krow & 7)));
          acc[ni] = __builtin_amdgcn_mfma_f32_16x16x32_bf16(qf, kf, acc[ni], 0, 0, 0);
        }
      }
      __syncthreads();
    }
#pragma unroll
    for (int r = 0; r < 4; ++r) {
      float mx = -1e30f;
#pragma unroll
      for (int ni = 0; ni < 16; ++ni) mx = fmaxf(mx, acc[ni][r]);
#pragma unroll
      for (int off = 1; off < 16; off <<= 1) mx = fmaxf(mx, __shfl_xor(mx, off, 64));
      float s = 0.0f;
#pragma unroll
      for (int ni = 0; ni < 16; ++ni) {
        float p = __expf((acc[ni][r] - mx) * sc);
        acc[ni][r] = p;
        s += p;
      }
#pragma unroll
      for (int off = 1; off < 16; off <<= 1) s += __shfl_xor(s, off, 64);
      float f = invNS / s;
#pragma unroll
      for (int ni = 0; ni < 16; ++ni) avg[ni][r] += acc[ni][r] * f;
    }
  }
  unsigned short* Of = Aout + (((long)b * 4 + m0idx) * 256 + t) * 64;
#pragma unroll
  for (int r = 0; r < 4; ++r) {
    ushort8 lo, hi;
#pragma unroll
    for (int j = 0; j < 8; ++j) { lo[j] = f2bf(avg[j][r]); hi[j] = f2bf(avg[8 + j][r]); }
    *(ushort8*)(Of + r * 16) = lo;
    *(ushort8*)(Of + r * 16 + 8) = hi;
  }
}

// ------- pass B: scale1 scores + softmax + gate combine -> ATTN (unchanged) ---------
__global__ void __launch_bounds__(256) scores1_gate(
    const unsigned short* __restrict__ QK1, const unsigned short* __restrict__ A2P,
    const unsigned short* __restrict__ A3P, unsigned short* __restrict__ ATTN) {
  __shared__ unsigned short Qs[64 * 64];
  __shared__ unsigned short Ks[256 * 64];
  const int bid = blockIdx.x;
  const int b = bid >> 2, m0 = (bid & 3) * 64;
  const unsigned short* base = QK1 + ((long)b << 16);
  const int t = threadIdx.x, lane = t & 63, w = t >> 6;
  const int r8 = t >> 3, sl = t & 7;
  f32x4 acc[16] = {};
  for (int kc = 0; kc < 2; ++kc) {
#pragma unroll
    for (int i = 0; i < 2; ++i) {
      int row = i * 32 + r8;
      gl2lds16(base + (long)(m0 + row) * 256 + kc * 64 + (sl ^ (row & 7)) * 8,
               (char*)Qs + i * 4096 + t * 16);
    }
#pragma unroll
    for (int i = 0; i < 8; ++i) {
      int row = i * 32 + r8;
      gl2lds16(base + (long)row * 256 + 128 + kc * 64 + (sl ^ (row & 7)) * 8,
               (char*)Ks + i * 4096 + t * 16);
    }
    __syncthreads();
#pragma unroll
    for (int kk = 0; kk < 2; ++kk) {
      const int qrow = w * 16 + (lane & 15);
      const int slot = kk * 4 + (lane >> 4);
      bf16x8 qf = *(const bf16x8*)((char*)Qs + qrow * 128 + 16 * (slot ^ (qrow & 7)));
#pragma unroll
      for (int ni = 0; ni < 16; ++ni) {
        int krow = ni * 16 + (lane & 15);
        bf16x8 kf = *(const bf16x8*)((char*)Ks + krow * 128 + 16 * (slot ^ (krow & 7)));
        acc[ni] = __builtin_amdgcn_mfma_f32_16x16x32_bf16(qf, kf, acc[ni], 0, 0, 0);
      }
    }
    __syncthreads();
  }
  const float sc = 0.088388347648318447f;
#pragma unroll
  for (int r = 0; r < 4; ++r) {
    float mx = -1e30f;
#pragma unroll
    for (int ni = 0; ni < 16; ++ni) mx = fmaxf(mx, acc[ni][r]);
#pragma unroll
    for (int off = 1; off < 16; off <<= 1) mx = fmaxf(mx, __shfl_xor(mx, off, 64));
    float s = 0.0f;
#pragma unroll
    for (int ni = 0; ni < 16; ++ni) {
      float p = __expf((acc[ni][r] - mx) * sc);
      acc[ni][r] = p;
      s += p;
    }
#pragma unroll
    for (int off = 1; off < 16; off <<= 1) s += __shfl_xor(s, off, 64);
    float inv = 1.0f / s;
    long fidx = ((long)bid * 256 + t) * 64 + r * 16;
    ushort8 a2l = *(const ushort8*)(A2P + fidx);
    ushort8 a2h = *(const ushort8*)(A2P + fidx + 8);
    ushort8 a3l = *(const ushort8*)(A3P + fidx);
    ushort8 a3h = *(const ushort8*)(A3P + fidx + 8);
    int row = m0 + w * 16 + (lane >> 4) * 4 + r;
    long roff = ((long)b << 16) + (long)row * 256 + (lane & 15);
#pragma unroll
    for (int j = 0; j < 8; ++j) {
      float A1 = acc[j][r] * inv;
      float A2 = bf2f(a2l[j]), A3 = bf2f(a3l[j]);
      float m = fmaxf(A1, fmaxf(A2, A3));
      float e1 = __expf(A1 - m), e2 = __expf(A2 - m), e3 = __expf(A3 - m);
      ATTN[roff + j * 16] = f2bf((A1 * e1 + A2 * e2 + A3 * e3) / (e1 + e2 + e3));
    }
#pragma unroll
    for (int j = 0; j < 8; ++j) {
      float A1 = acc[8 + j][r] * inv;
      float A2 = bf2f(a2h[j]), A3 = bf2f(a3h[j]);
      float m = fmaxf(A1, fmaxf(A2, A3));
      float e1 = __expf(A1 - m), e2 = __expf(A2 - m), e3 = __expf(A3 - m);
      ATTN[roff + (8 + j) * 16] = f2bf((A1 * e1 + A2 * e2 + A3 * e3) / (e1 + e2 + e3));
    }
  }
}

// ------- 4-wave 128x128 NT GEMM, single-buf 32KB, swapped mfma, packed stores -------
// BIASMODE: 0 none, 2 per-row. Out row-major [M][ldo].
template <int F32OUT, int BIASMODE>
__global__ void __launch_bounds__(256) gemm4(
    const unsigned short* __restrict__ A, const unsigned short* __restrict__ B,
    void* __restrict__ OutV, const float* __restrict__ bias,
    int lda, int ldb, int K, long astr, long bstr, long ostr, int ldo) {
  extern __shared__ char smem[];  // A [128][64]sw 16K + B [128][64]sw 16K
  const int t = threadIdx.x, lane = t & 63, wid = t >> 6;
  const int wm = (wid >> 1) * 64, wn = (wid & 1) * 64;
  const int m0 = blockIdx.y * 128, n0 = blockIdx.x * 128;
  const int bz = blockIdx.z;
  const unsigned short* Ab = A + (long)bz * astr + (long)m0 * lda;
  const unsigned short* Bb = B + (long)bz * bstr + (long)n0 * ldb;
  const int srow = t >> 3, ssl = t & 7;
  f32x4 acc[4][4] = {};
  for (int k0 = 0; k0 < K; k0 += 64) {
#pragma unroll
    for (int i = 0; i < 4; ++i) {
      int row = i * 32 + srow;
      int scol = (ssl ^ (row & 7)) * 8;
      gl2lds16(Ab + (long)row * lda + k0 + scol, smem + i * 4096 + t * 16);
      gl2lds16(Bb + (long)row * ldb + k0 + scol, smem + 16384 + i * 4096 + t * 16);
    }
    __syncthreads();
#pragma unroll
    for (int kk = 0; kk < 2; ++kk) {
      const int slot = kk * 4 + (lane >> 4);
      bf16x8 af[4], bfr[4];
#pragma unroll
      for (int mi = 0; mi < 4; ++mi) {
        int row = wm + mi * 16 + (lane & 15);
        af[mi] = *(const bf16x8*)(smem + row * 128 + 16 * (slot ^ (row & 7)));
      }
#pragma unroll
      for (int ni = 0; ni < 4; ++ni) {
        int row = wn + ni * 16 + (lane & 15);
        bfr[ni] = *(const bf16x8*)(smem + 16384 + row * 128 + 16 * (slot ^ (row & 7)));
      }
#pragma unroll
      for (int mi = 0; mi < 4; ++mi)
#pragma unroll
        for (int ni = 0; ni < 4; ++ni)
          acc[mi][ni] = __builtin_amdgcn_mfma_f32_16x16x32_bf16(bfr[ni], af[mi], acc[mi][ni], 0, 0, 0);
    }
    __syncthreads();
  }
#pragma unroll
  for (int mi = 0; mi < 4; ++mi) {
    int rowm = m0 + wm + mi * 16 + (lane & 15);
    float rb = (BIASMODE == 2) ? bias[rowm] : 0.0f;
#pragma unroll
    for (int ni = 0; ni < 4; ++ni) {
      int ncb = n0 + wn + ni * 16 + (lane >> 4) * 4;
      if constexpr (F32OUT) {
        f32x4 v = {acc[mi][ni][0] + rb, acc[mi][ni][1] + rb,
                   acc[mi][ni][2] + rb, acc[mi][ni][3] + rb};
        *(f32x4*)((float*)OutV + (long)bz * ostr + (long)rowm * ldo + ncb) = v;
      } else {
        *(unsigned long long*)((unsigned short*)OutV + (long)bz * ostr + (long)rowm * ldo + ncb) =
            pack4bf(acc[mi][ni][0] + rb, acc[mi][ni][1] + rb,
                    acc[mi][ni][2] + rb, acc[mi][ni][3] + rb);
      }
    }
  }
}

// ------------------------------------------------------------------------------------
extern "C" void kernel_launch(void* const* d_in, const int* in_sizes, int n_in,
                              void* d_out, int out_size, void* d_ws, size_t ws_size,
                              hipStream_t stream) {
  (void)in_sizes; (void)n_in; (void)out_size; (void)ws_size;
  const float* x   = (const float*)d_in[0];
  const float* wq1 = (const float*)d_in[1];
  const float* bq1 = (const float*)d_in[2];
  const float* wk1 = (const float*)d_in[3];
  const float* bk1 = (const float*)d_in[4];
  const float* wq2 = (const float*)d_in[5];
  const float* bq2 = (const float*)d_in[6];
  const float* wk2 = (const float*)d_in[7];
  const float* bk2 = (const float*)d_in[8];
  const float* wq3 = (const float*)d_in[9];
  const float* bq3 = (const float*)d_in[10];
  const float* wk3 = (const float*)d_in[11];
  const float* bk3 = (const float*)d_in[12];
  const float* wv  = (const float*)d_in[13];
  const float* bv  = (const float*)d_in[14];
  const float* wo  = (const float*)d_in[15];
  const float* bo  = (const float*)d_in[16];
  char* ws = (char*)d_ws;

  // workspace layout (bytes), peak ~94.4 MB
  unsigned short* XT   = (unsigned short*)(ws + 0);         // [64][256][512] 16.8MB
  unsigned short* WQK1 = (unsigned short*)(ws + 16777216);  // [256][512]
  unsigned short* WQK2 = (unsigned short*)(ws + 17039360);  // [256][256]
  unsigned short* WQK3 = (unsigned short*)(ws + 17170432);  // [256][128]
  unsigned short* WOT  = (unsigned short*)(ws + 17235968);  // [512][512] wo^T
  unsigned short* WVNT = (unsigned short*)(ws + 17760256);  // [512][512] wv row-major
  unsigned short* WVOT = (unsigned short*)(ws + 18284544);  // [512][512] (wv@wo)^T
  float*          BVO  = (float*)(ws + 18808832);           // [512] bv@wo
  unsigned short* QK1  = (unsigned short*)(ws + 18876416);  // [64][256][256]  (dead after passB)
  unsigned short* QK2  = (unsigned short*)(ws + 27265024);  // [128][256][256] (dead after passA)
  unsigned short* QK3  = (unsigned short*)(ws + 44042240);  // [256][256][256] (dead after passA)
  unsigned short* A2P  = (unsigned short*)(ws + 77596672);  // fragment layout
  unsigned short* A3P  = (unsigned short*)(ws + 85985280);  // fragment layout, end 94,373,888
  unsigned short* ATTN = (unsigned short*)(ws + 44042240);  // [64][256][256] over dead QK3
  unsigned short* XVT  = (unsigned short*)(ws + 18876416);  // [64][512][256] over dead QK1/QK2

  tcast_all<<<dim3(2296), dim3(256), 0, stream>>>(
      x, wq1, wk1, wq2, wk2, wq3, wk3, wv, wo,
      XT, WQK1, WQK2, WQK3, WVNT, WOT);

  proj4<<<dim3(2, 2, 453), dim3(256), 32768, stream>>>(
      XT, WQK1, WQK2, WQK3, WOT, WVNT, WVOT, BVO, bv,
      QK1, QK2, QK3, bq1, bk1, bq2, bk2, bq3, bk3);

  scores_mean<<<dim3(512), dim3(256), 0, stream>>>(QK2, QK3, A2P, A3P);
  scores1_gate<<<dim3(256), dim3(256), 0, stream>>>(QK1, A2P, A3P, ATTN);

  // XVT[b][p][d] = sum_s WVOT[p][s]*XT[b][d][s] + BVO[p]   (row-bias)
  gemm4<0, 2><<<dim3(2, 4, 64), dim3(256), 32768, stream>>>(
      WVOT, XT, XVT, BVO, 512, 512, 512, 0, 131072, 131072, 256);
  // out[b][p][c] = sum_d XVT[b][p][d]*ATTN[b][c][d] + bo[p] (row-bias, fp32)
  gemm4<1, 2><<<dim3(2, 4, 64), dim3(256), 32768, stream>>>(
      XVT, ATTN, d_out, bo, 256, 256, 256, 131072, 65536, 131072, 256);
}

// Round 12
// 122.057 us; speedup vs baseline: 1.2930x; 1.2930x over previous
//
#include <hip/hip_runtime.h>
#include <hip/hip_bf16.h>

// ChannelDeAttention: B=64,S=512,C=256,H=128,P=512
// bf16 MFMA (16x16x32), fp32 accum. 6 launches. XOR-swizzled LDS.
// R12 = R10 structure (8-wave, BN=256, issue-early dbuf) with BK=32:
// 48KB LDS -> 3 blocks/CU so barrier drains are backfilled by other blocks.

typedef __attribute__((ext_vector_type(8))) short bf16x8;
typedef __attribute__((ext_vector_type(4))) float f32x4;
typedef __attribute__((ext_vector_type(8))) unsigned short ushort8;

typedef __attribute__((address_space(1))) void* as1vp;
typedef __attribute__((address_space(3))) void* as3vp;

__device__ __forceinline__ void gl2lds16(const void* g, void* l) {
  __builtin_amdgcn_global_load_lds((as1vp)(void*)g, (as3vp)l, 16, 0, 0);
}

__device__ __forceinline__ float bf2f(unsigned short u) {
  union { unsigned int i; float f; } v; v.i = ((unsigned int)u) << 16; return v.f;
}
__device__ __forceinline__ unsigned short f2bf(float f) {
  union { float f; unsigned int i; } v; v.f = f;
  unsigned int r = v.i + 0x7FFFu + ((v.i >> 16) & 1u);
  return (unsigned short)(r >> 16);
}
__device__ __forceinline__ unsigned long long pack4bf(float a, float b, float c, float d) {
  return (unsigned long long)f2bf(a) | ((unsigned long long)f2bf(b) << 16) |
         ((unsigned long long)f2bf(c) << 32) | ((unsigned long long)f2bf(d) << 48);
}

// BK=32 tile helpers: rows are 32 bf16 = 64B; 4 16B slots/row.
// LDS slot s holds global k-block (s ^ ((row>>1)&3)); 2 lanes/bank on reads (free).
__device__ __forceinline__ int swz32(int row, int s) { return s ^ ((row >> 1) & 3); }

// ------- transposes (x + 5 weight mats) + plain wv cast, one launch -----------------
__global__ void __launch_bounds__(256) tcast_all(
    const float* __restrict__ x,
    const float* __restrict__ wq1, const float* __restrict__ wk1,
    const float* __restrict__ wq2, const float* __restrict__ wk2,
    const float* __restrict__ wq3, const float* __restrict__ wk3,
    const float* __restrict__ wv, const float* __restrict__ wo,
    unsigned short* __restrict__ XT,
    unsigned short* __restrict__ W1, unsigned short* __restrict__ W2,
    unsigned short* __restrict__ W3, unsigned short* __restrict__ WVNT,
    unsigned short* __restrict__ WOT) {
  const int bid = blockIdx.x;
  const int t = threadIdx.x;
  if (bid >= 2168) {  // plain-cast wv to bf16 row-major (coalesced)
    long i0 = (long)(bid - 2168) * 2048 + t * 8;
    f32x4 a = *(const f32x4*)(wv + i0);
    f32x4 b = *(const f32x4*)(wv + i0 + 4);
    ushort8 o;
#pragma unroll
    for (int j = 0; j < 4; ++j) { o[j] = f2bf(a[j]); o[4 + j] = f2bf(b[j]); }
    *(ushort8*)(WVNT + i0) = o;
    return;
  }
  __shared__ float lds[64][68];
  const float* S; unsigned short* D; int R, Cc, r0, c0, rowoff = 0;
  if (bid < 2048) {
    int bz = bid >> 5, i = bid & 31;
    S = x + (long)bz * 131072; D = XT + (long)bz * 131072;
    R = 512; Cc = 256; r0 = (i & 7) * 64; c0 = (i >> 3) * 64;
  } else {
    int wb = bid - 2048;
    if (wb < 32) {
      int m = wb >> 4, i = wb & 15;
      S = m ? wk1 : wq1; D = W1; R = 512; Cc = 128;
      r0 = (i & 7) * 64; c0 = (i >> 3) * 64; rowoff = m * 128;
    } else if (wb < 48) {
      int m = (wb - 32) >> 3, i = (wb - 32) & 7;
      S = m ? wk2 : wq2; D = W2; R = 256; Cc = 128;
      r0 = (i & 3) * 64; c0 = (i >> 2) * 64; rowoff = m * 128;
    } else if (wb < 56) {
      int m = (wb - 48) >> 2, i = (wb - 48) & 3;
      S = m ? wk3 : wq3; D = W3; R = 128; Cc = 128;
      r0 = (i & 1) * 64; c0 = (i >> 1) * 64; rowoff = m * 128;
    } else {
      int i = wb - 56; S = wo; D = WOT; R = 512; Cc = 512;
      r0 = (i & 7) * 64; c0 = (i >> 3) * 64;
    }
  }
  {
    const int row = t >> 2, cq = (t & 3) * 16;
    const float* Sp = S + (long)(r0 + row) * Cc + c0 + cq;
#pragma unroll
    for (int j = 0; j < 4; ++j)
      *(f32x4*)&lds[row][cq + j * 4] = *(const f32x4*)(Sp + j * 4);
  }
  __syncthreads();
  {
    const int rq = (t & 15) * 4, ccb = t >> 4;
#pragma unroll
    for (int j = 0; j < 4; ++j) {
      int cc = ccb + j * 16;
      *(unsigned long long*)(D + (long)(c0 + cc + rowoff) * R + r0 + rq) =
          pack4bf(lds[rq][cc], lds[rq + 1][cc], lds[rq + 2][cc], lds[rq + 3][cc]);
    }
  }
}

// ------- fused Q/K projections + WVOT SQ-gemm blocks + BVO blocks, one launch -------
// grid (1,2,458): z<448 proj; z in [448,456) WVOT; z>=456 BVO.
// BK=32 dbuf: per buf 24KB (proj: A[128][32] 8K + B[256][32] 16K); total 48KB.
__global__ void __launch_bounds__(512) proj_all8(
    const unsigned short* __restrict__ XT,
    const unsigned short* __restrict__ W1, const unsigned short* __restrict__ W2,
    const unsigned short* __restrict__ W3,
    const unsigned short* __restrict__ WOT, const unsigned short* __restrict__ WVNT,
    unsigned short* __restrict__ WVOT, float* __restrict__ BVO,
    const float* __restrict__ bv,
    unsigned short* __restrict__ Q1, unsigned short* __restrict__ Q2,
    unsigned short* __restrict__ Q3,
    const float* __restrict__ bq1, const float* __restrict__ bk1,
    const float* __restrict__ bq2, const float* __restrict__ bk2,
    const float* __restrict__ bq3, const float* __restrict__ bk3) {
  extern __shared__ char smem[];
  const int z = blockIdx.z;
  const int t = threadIdx.x, lane = t & 63, wid = t >> 6;

  if (z >= 456) {  // ---- BVO[p] = sum_s bv[s] * WOT[p][s]
    int p0 = ((z - 456) * 2 + blockIdx.y) * 128 + wid * 16;
    f32x4 b0 = *(const f32x4*)(bv + lane * 8);
    f32x4 b1 = *(const f32x4*)(bv + lane * 8 + 4);
#pragma unroll
    for (int i = 0; i < 16; ++i) {
      int p = p0 + i;
      bf16x8 wrow = *(const bf16x8*)(WOT + (long)p * 512 + lane * 8);
      float s = 0.0f;
#pragma unroll
      for (int j = 0; j < 4; ++j) {
        s += b0[j] * bf2f((unsigned short)wrow[j]);
        s += b1[j] * bf2f((unsigned short)wrow[4 + j]);
      }
#pragma unroll
      for (int off = 1; off < 64; off <<= 1) s += __shfl_xor(s, off, 64);
      if (lane == 0) BVO[p] = s;
    }
    return;
  }

  const int rS = t >> 2, sS = t & 3;  // staging row/slot (per 512 threads, 128 rows)

  if (z >= 448) {  // ---- WVOT[p][s] = sum_t WOT[p][t]*wv[s][t], SQ128, BK=32 dbuf
    const int w = (z - 448) * 2 + blockIdx.y;
    const int m0 = (w >> 2) * 128, n0 = (w & 3) * 128;
    const unsigned short* Ab = WOT + (long)m0 * 512;
    const unsigned short* Bb = WVNT + (long)n0 * 512;
    const int wmb = (wid >> 2) * 64, wnb = (wid & 3) * 32;
    f32x4 acc[4][2] = {};
    auto stageS = [&](int buf, int k0) {
      char* s = smem + buf * 24576;
      gl2lds16(Ab + (long)rS * 512 + k0 + (swz32(rS, sS) << 3), s + t * 16);
      gl2lds16(Bb + (long)rS * 512 + k0 + (swz32(rS, sS) << 3), s + 8192 + t * 16);
    };
    stageS(0, 0);
    __syncthreads();
    int cur = 0;
    for (int k0 = 0; k0 < 512; k0 += 32) {
      if (k0 + 32 < 512) stageS(cur ^ 1, k0 + 32);
      const char* s = smem + cur * 24576;
      const int kb = lane >> 4;
      bf16x8 af[4], bfr[2];
#pragma unroll
      for (int mi = 0; mi < 4; ++mi) {
        int row = wmb + mi * 16 + (lane & 15);
        af[mi] = *(const bf16x8*)(s + row * 64 + (swz32(row, kb) << 4));
      }
#pragma unroll
      for (int ni = 0; ni < 2; ++ni) {
        int row = wnb + ni * 16 + (lane & 15);
        bfr[ni] = *(const bf16x8*)(s + 8192 + row * 64 + (swz32(row, kb) << 4));
      }
#pragma unroll
      for (int mi = 0; mi < 4; ++mi)
#pragma unroll
        for (int ni = 0; ni < 2; ++ni)
          acc[mi][ni] = __builtin_amdgcn_mfma_f32_16x16x32_bf16(af[mi], bfr[ni], acc[mi][ni], 0, 0, 0);
      __syncthreads();
      cur ^= 1;
    }
#pragma unroll
    for (int ni = 0; ni < 2; ++ni) {
      int col = n0 + wnb + ni * 16 + (lane & 15);
#pragma unroll
      for (int mi = 0; mi < 4; ++mi) {
        int rowb = m0 + wmb + mi * 16 + (lane >> 4) * 4;
#pragma unroll
        for (int r = 0; r < 4; ++r)
          WVOT[(long)(rowb + r) * 512 + col] = f2bf(acc[mi][ni][r]);
      }
    }
    return;
  }

  // ---- normal proj path ----
  const unsigned short* Ab; const unsigned short* Bw; unsigned short* O;
  const float *bq, *bk; int K;
  if (z < 64) {
    K = 512; Bw = W1; O = Q1 + (long)z * 65536; bq = bq1; bk = bk1;
    Ab = XT + (long)z * 131072;
  } else if (z < 192) {
    int u = z - 64; K = 256; Bw = W2; O = Q2 + (long)u * 65536; bq = bq2; bk = bk2;
    Ab = XT + (long)(u >> 1) * 131072 + (u & 1) * 256;
  } else {
    int u = z - 192; K = 128; Bw = W3; O = Q3 + (long)u * 65536; bq = bq3; bk = bk3;
    Ab = XT + (long)(u >> 2) * 131072 + (u & 3) * 128;
  }
  const int wmb = (wid >> 2) * 64, wnb = (wid & 3) * 64;
  const int m0 = blockIdx.y * 128;
  Ab += (long)m0 * 512;

  auto stage = [&](int buf, int k0) {
    char* s = smem + buf * 24576;
    gl2lds16(Ab + (long)rS * 512 + k0 + (swz32(rS, sS) << 3), s + t * 16);
#pragma unroll
    for (int i = 0; i < 2; ++i) {
      int row = i * 128 + rS;
      gl2lds16(Bw + (long)row * K + k0 + (swz32(row, sS) << 3),
               s + 8192 + i * 8192 + t * 16);
    }
  };

  f32x4 acc[4][4] = {};
  stage(0, 0);
  __syncthreads();
  int cur = 0;
  for (int k0 = 0; k0 < K; k0 += 32) {
    if (k0 + 32 < K) stage(cur ^ 1, k0 + 32);
    const char* s = smem + cur * 24576;
    const int kb = lane >> 4;
    bf16x8 af[4], bfr[4];
#pragma unroll
    for (int mi = 0; mi < 4; ++mi) {
      int row = wmb + mi * 16 + (lane & 15);
      af[mi] = *(const bf16x8*)(s + row * 64 + (swz32(row, kb) << 4));
    }
#pragma unroll
    for (int ni = 0; ni < 4; ++ni) {
      int row = wnb + ni * 16 + (lane & 15);
      bfr[ni] = *(const bf16x8*)(s + 8192 + row * 64 + (swz32(row, kb) << 4));
    }
#pragma unroll
    for (int mi = 0; mi < 4; ++mi)
#pragma unroll
      for (int ni = 0; ni < 4; ++ni)
        acc[mi][ni] = __builtin_amdgcn_mfma_f32_16x16x32_bf16(af[mi], bfr[ni], acc[mi][ni], 0, 0, 0);
    __syncthreads();
    cur ^= 1;
  }
#pragma unroll
  for (int ni = 0; ni < 4; ++ni) {
    int colL = wnb + ni * 16 + (lane & 15);
    float bv_ = (colL < 128) ? bq[colL] : bk[colL - 128];
#pragma unroll
    for (int mi = 0; mi < 4; ++mi) {
      int rowb = m0 + wmb + mi * 16 + (lane >> 4) * 4;
#pragma unroll
      for (int r = 0; r < 4; ++r)
        O[(long)(rowb + r) * 256 + colL] = f2bf(acc[mi][ni][r] + bv_);
    }
  }
}

// ------- pass A: scales 2+3 scores + softmax + sub-batch mean (unchanged) -----------
__global__ void __launch_bounds__(256) scores_mean(
    const unsigned short* __restrict__ QK2, const unsigned short* __restrict__ QK3,
    unsigned short* __restrict__ A2P, unsigned short* __restrict__ A3P) {
  __shared__ unsigned short Qs[64 * 64];
  __shared__ unsigned short Ks[256 * 64];
  const int bid = blockIdx.x;
  const unsigned short* QK; unsigned short* Aout; int NS, b, m0idx;
  if (bid < 256) { NS = 4; b = bid >> 2; m0idx = bid & 3; QK = QK3; Aout = A3P; }
  else { int u = bid - 256; NS = 2; b = u >> 2; m0idx = u & 3; QK = QK2; Aout = A2P; }
  const int m0 = m0idx * 64;
  const int t = threadIdx.x, lane = t & 63, w = t >> 6;
  const int r8 = t >> 3, sl = t & 7;
  const float sc = 0.088388347648318447f;
  const float invNS = 1.0f / NS;
  f32x4 avg[16] = {};
  for (int h = 0; h < NS; ++h) {
    const unsigned short* base = QK + ((long)(b * NS + h) << 16);
    f32x4 acc[16] = {};
    for (int kc = 0; kc < 2; ++kc) {
#pragma unroll
      for (int i = 0; i < 2; ++i) {
        int row = i * 32 + r8;
        gl2lds16(base + (long)(m0 + row) * 256 + kc * 64 + (sl ^ (row & 7)) * 8,
                 (char*)Qs + i * 4096 + t * 16);
      }
#pragma unroll
      for (int i = 0; i < 8; ++i) {
        int row = i * 32 + r8;
        gl2lds16(base + (long)row * 256 + 128 + kc * 64 + (sl ^ (row & 7)) * 8,
                 (char*)Ks + i * 4096 + t * 16);
      }
      __syncthreads();
#pragma unroll
      for (int kk = 0; kk < 2; ++kk) {
        const int qrow = w * 16 + (lane & 15);
        const int slot = kk * 4 + (lane >> 4);
        bf16x8 qf = *(const bf16x8*)((char*)Qs + qrow * 128 + 16 * (slot ^ (qrow & 7)));
#pragma unroll
        for (int ni = 0; ni < 16; ++ni) {
          int krow = ni * 16 + (lane & 15);
          bf16x8 kf = *(const bf16x8*)((char*)Ks + krow * 128 + 16 * (slot ^ (krow & 7)));
          acc[ni] = __builtin_amdgcn_mfma_f32_16x16x32_bf16(qf, kf, acc[ni], 0, 0, 0);
        }
      }
      __syncthreads();
    }
#pragma unroll
    for (int r = 0; r < 4; ++r) {
      float mx = -1e30f;
#pragma unroll
      for (int ni = 0; ni < 16; ++ni) mx = fmaxf(mx, acc[ni][r]);
#pragma unroll
      for (int off = 1; off < 16; off <<= 1) mx = fmaxf(mx, __shfl_xor(mx, off, 64));
      float s = 0.0f;
#pragma unroll
      for (int ni = 0; ni < 16; ++ni) {
        float p = __expf((acc[ni][r] - mx) * sc);
        acc[ni][r] = p;
        s += p;
      }
#pragma unroll
      for (int off = 1; off < 16; off <<= 1) s += __shfl_xor(s, off, 64);
      float f = invNS / s;
#pragma unroll
      for (int ni = 0; ni < 16; ++ni) avg[ni][r] += acc[ni][r] * f;
    }
  }
  unsigned short* Of = Aout + (((long)b * 4 + m0idx) * 256 + t) * 64;
#pragma unroll
  for (int r = 0; r < 4; ++r) {
    ushort8 lo, hi;
#pragma unroll
    for (int j = 0; j < 8; ++j) { lo[j] = f2bf(avg[j][r]); hi[j] = f2bf(avg[8 + j][r]); }
    *(ushort8*)(Of + r * 16) = lo;
    *(ushort8*)(Of + r * 16 + 8) = hi;
  }
}

// ------- pass B: scale1 scores + softmax + gate combine -> ATTN (unchanged) ---------
__global__ void __launch_bounds__(256) scores1_gate(
    const unsigned short* __restrict__ QK1, const unsigned short* __restrict__ A2P,
    const unsigned short* __restrict__ A3P, unsigned short* __restrict__ ATTN) {
  __shared__ unsigned short Qs[64 * 64];
  __shared__ unsigned short Ks[256 * 64];
  const int bid = blockIdx.x;
  const int b = bid >> 2, m0 = (bid & 3) * 64;
  const unsigned short* base = QK1 + ((long)b << 16);
  const int t = threadIdx.x, lane = t & 63, w = t >> 6;
  const int r8 = t >> 3, sl = t & 7;
  f32x4 acc[16] = {};
  for (int kc = 0; kc < 2; ++kc) {
#pragma unroll
    for (int i = 0; i < 2; ++i) {
      int row = i * 32 + r8;
      gl2lds16(base + (long)(m0 + row) * 256 + kc * 64 + (sl ^ (row & 7)) * 8,
               (char*)Qs + i * 4096 + t * 16);
    }
#pragma unroll
    for (int i = 0; i < 8; ++i) {
      int row = i * 32 + r8;
      gl2lds16(base + (long)row * 256 + 128 + kc * 64 + (sl ^ (row & 7)) * 8,
               (char*)Ks + i * 4096 + t * 16);
    }
    __syncthreads();
#pragma unroll
    for (int kk = 0; kk < 2; ++kk) {
      const int qrow = w * 16 + (lane & 15);
      const int slot = kk * 4 + (lane >> 4);
      bf16x8 qf = *(const bf16x8*)((char*)Qs + qrow * 128 + 16 * (slot ^ (qrow & 7)));
#pragma unroll
      for (int ni = 0; ni < 16; ++ni) {
        int krow = ni * 16 + (lane & 15);
        bf16x8 kf = *(const bf16x8*)((char*)Ks + krow * 128 + 16 * (slot ^ (krow & 7)));
        acc[ni] = __builtin_amdgcn_mfma_f32_16x16x32_bf16(qf, kf, acc[ni], 0, 0, 0);
      }
    }
    __syncthreads();
  }
  const float sc = 0.088388347648318447f;
#pragma unroll
  for (int r = 0; r < 4; ++r) {
    float mx = -1e30f;
#pragma unroll
    for (int ni = 0; ni < 16; ++ni) mx = fmaxf(mx, acc[ni][r]);
#pragma unroll
    for (int off = 1; off < 16; off <<= 1) mx = fmaxf(mx, __shfl_xor(mx, off, 64));
    float s = 0.0f;
#pragma unroll
    for (int ni = 0; ni < 16; ++ni) {
      float p = __expf((acc[ni][r] - mx) * sc);
      acc[ni][r] = p;
      s += p;
    }
#pragma unroll
    for (int off = 1; off < 16; off <<= 1) s += __shfl_xor(s, off, 64);
    float inv = 1.0f / s;
    long fidx = ((long)bid * 256 + t) * 64 + r * 16;
    ushort8 a2l = *(const ushort8*)(A2P + fidx);
    ushort8 a2h = *(const ushort8*)(A2P + fidx + 8);
    ushort8 a3l = *(const ushort8*)(A3P + fidx);
    ushort8 a3h = *(const ushort8*)(A3P + fidx + 8);
    int row = m0 + w * 16 + (lane >> 4) * 4 + r;
    long roff = ((long)b << 16) + (long)row * 256 + (lane & 15);
#pragma unroll
    for (int j = 0; j < 8; ++j) {
      float A1 = acc[j][r] * inv;
      float A2 = bf2f(a2l[j]), A3 = bf2f(a3l[j]);
      float m = fmaxf(A1, fmaxf(A2, A3));
      float e1 = __expf(A1 - m), e2 = __expf(A2 - m), e3 = __expf(A3 - m);
      ATTN[roff + j * 16] = f2bf((A1 * e1 + A2 * e2 + A3 * e3) / (e1 + e2 + e3));
    }
#pragma unroll
    for (int j = 0; j < 8; ++j) {
      float A1 = acc[8 + j][r] * inv;
      float A2 = bf2f(a2h[j]), A3 = bf2f(a3h[j]);
      float m = fmaxf(A1, fmaxf(A2, A3));
      float e1 = __expf(A1 - m), e2 = __expf(A2 - m), e3 = __expf(A3 - m);
      ATTN[roff + (8 + j) * 16] = f2bf((A1 * e1 + A2 * e2 + A3 * e3) / (e1 + e2 + e3));
    }
  }
}

// ------- 8-wave TALL(256x128) NT GEMM, BK=32 dbuf (48KB -> 3 blocks/CU) -------------
// BIASMODE: 0 none, 2 per-row. Out row-major [M][ldo].
template <int F32OUT, int BIASMODE>
__global__ void __launch_bounds__(512) gemm8(
    const unsigned short* __restrict__ A, const unsigned short* __restrict__ B,
    void* __restrict__ OutV, const float* __restrict__ bias,
    int lda, int ldb, int K, long astr, long bstr, long ostr, int ldo) {
  extern __shared__ char smem[];  // per buf 24KB: A[256][32] 16K + B[128][32] 8K
  const int t = threadIdx.x, lane = t & 63, wid = t >> 6;
  const int wmb = (wid >> 1) * 64, wnb = (wid & 1) * 64;
  const int m0 = blockIdx.y * 256, n0 = blockIdx.x * 128;
  const int bz = blockIdx.z;
  const unsigned short* Ab = A + (long)bz * astr + (long)m0 * lda;
  const unsigned short* Bb = B + (long)bz * bstr + (long)n0 * ldb;
  const int rS = t >> 2, sS = t & 3;

  auto stage = [&](int buf, int k0) {
    char* s = smem + buf * 24576;
#pragma unroll
    for (int i = 0; i < 2; ++i) {
      int row = i * 128 + rS;
      gl2lds16(Ab + (long)row * lda + k0 + (swz32(row, sS) << 3),
               s + i * 8192 + t * 16);
    }
    gl2lds16(Bb + (long)rS * ldb + k0 + (swz32(rS, sS) << 3), s + 16384 + t * 16);
  };

  f32x4 acc[4][4] = {};
  stage(0, 0);
  __syncthreads();
  int cur = 0;
  for (int k0 = 0; k0 < K; k0 += 32) {
    if (k0 + 32 < K) stage(cur ^ 1, k0 + 32);
    const char* s = smem + cur * 24576;
    const int kb = lane >> 4;
    bf16x8 af[4], bfr[4];
#pragma unroll
    for (int mi = 0; mi < 4; ++mi) {
      int row = wmb + mi * 16 + (lane & 15);
      af[mi] = *(const bf16x8*)(s + row * 64 + (swz32(row, kb) << 4));
    }
#pragma unroll
    for (int ni = 0; ni < 4; ++ni) {
      int row = wnb + ni * 16 + (lane & 15);
      bfr[ni] = *(const bf16x8*)(s + 16384 + row * 64 + (swz32(row, kb) << 4));
    }
#pragma unroll
    for (int mi = 0; mi < 4; ++mi)
#pragma unroll
      for (int ni = 0; ni < 4; ++ni)
        acc[mi][ni] = __builtin_amdgcn_mfma_f32_16x16x32_bf16(af[mi], bfr[ni], acc[mi][ni], 0, 0, 0);
    __syncthreads();
    cur ^= 1;
  }
#pragma unroll
  for (int mi = 0; mi < 4; ++mi) {
    int rowb = m0 + wmb + mi * 16 + (lane >> 4) * 4;
    float rb[4];
#pragma unroll
    for (int r = 0; r < 4; ++r) rb[r] = (BIASMODE == 2) ? bias[rowb + r] : 0.0f;
#pragma unroll
    for (int ni = 0; ni < 4; ++ni) {
      int col = n0 + wnb + ni * 16 + (lane & 15);
#pragma unroll
      for (int r = 0; r < 4; ++r) {
        float v = acc[mi][ni][r] + rb[r];
        if constexpr (F32OUT)
          ((float*)OutV)[(long)bz * ostr + (long)(rowb + r) * ldo + col] = v;
        else
          ((unsigned short*)OutV)[(long)bz * ostr + (long)(rowb + r) * ldo + col] = f2bf(v);
      }
    }
  }
}

// ------------------------------------------------------------------------------------
extern "C" void kernel_launch(void* const* d_in, const int* in_sizes, int n_in,
                              void* d_out, int out_size, void* d_ws, size_t ws_size,
                              hipStream_t stream) {
  (void)in_sizes; (void)n_in; (void)out_size; (void)ws_size;
  const float* x   = (const float*)d_in[0];
  const float* wq1 = (const float*)d_in[1];
  const float* bq1 = (const float*)d_in[2];
  const float* wk1 = (const float*)d_in[3];
  const float* bk1 = (const float*)d_in[4];
  const float* wq2 = (const float*)d_in[5];
  const float* bq2 = (const float*)d_in[6];
  const float* wk2 = (const float*)d_in[7];
  const float* bk2 = (const float*)d_in[8];
  const float* wq3 = (const float*)d_in[9];
  const float* bq3 = (const float*)d_in[10];
  const float* wk3 = (const float*)d_in[11];
  const float* bk3 = (const float*)d_in[12];
  const float* wv  = (const float*)d_in[13];
  const float* bv  = (const float*)d_in[14];
  const float* wo  = (const float*)d_in[15];
  const float* bo  = (const float*)d_in[16];
  char* ws = (char*)d_ws;

  // workspace layout (bytes), peak ~94.4 MB
  unsigned short* XT   = (unsigned short*)(ws + 0);         // [64][256][512] 16.8MB
  unsigned short* WQK1 = (unsigned short*)(ws + 16777216);  // [256][512]
  unsigned short* WQK2 = (unsigned short*)(ws + 17039360);  // [256][256]
  unsigned short* WQK3 = (unsigned short*)(ws + 17170432);  // [256][128]
  unsigned short* WOT  = (unsigned short*)(ws + 17235968);  // [512][512] wo^T
  unsigned short* WVNT = (unsigned short*)(ws + 17760256);  // [512][512] wv row-major
  unsigned short* WVOT = (unsigned short*)(ws + 18284544);  // [512][512] (wv@wo)^T
  float*          BVO  = (float*)(ws + 18808832);           // [512] bv@wo
  unsigned short* QK1  = (unsigned short*)(ws + 18876416);  // [64][256][256]
  unsigned short* QK2  = (unsigned short*)(ws + 27265024);  // [128][256][256]
  unsigned short* QK3  = (unsigned short*)(ws + 44042240);  // [256][256][256]
  unsigned short* A2P  = (unsigned short*)(ws + 77596672);  // fragment layout
  unsigned short* A3P  = (unsigned short*)(ws + 85985280);  // fragment layout
  unsigned short* ATTN = (unsigned short*)(ws + 44042240);  // over dead QK3
  unsigned short* XVT  = (unsigned short*)(ws + 18876416);  // over dead QK1/QK2

  tcast_all<<<dim3(2296), dim3(256), 0, stream>>>(
      x, wq1, wk1, wq2, wk2, wq3, wk3, wv, wo,
      XT, WQK1, WQK2, WQK3, WVNT, WOT);

  proj_all8<<<dim3(1, 2, 458), dim3(512), 49152, stream>>>(
      XT, WQK1, WQK2, WQK3, WOT, WVNT, WVOT, BVO, bv,
      QK1, QK2, QK3, bq1, bk1, bq2, bk2, bq3, bk3);

  scores_mean<<<dim3(512), dim3(256), 0, stream>>>(QK2, QK3, A2P, A3P);
  scores1_gate<<<dim3(256), dim3(256), 0, stream>>>(QK1, A2P, A3P, ATTN);

  // XVT[b][p][d] = sum_s WVOT[p][s]*XT[b][d][s] + BVO[p]   (row-bias)
  gemm8<0, 2><<<dim3(2, 2, 64), dim3(512), 49152, stream>>>(
      WVOT, XT, XVT, BVO, 512, 512, 512, 0, 131072, 131072, 256);
  // out[b][p][c] = sum_d XVT[b][p][d]*ATTN[b][c][d] + bo[p] (row-bias, fp32)
  gemm8<1, 2><<<dim3(2, 2, 64), dim3(512), 49152, stream>>>(
      XVT, ATTN, d_out, bo, 256, 256, 256, 131072, 65536, 131072, 256);
}

// Round 13
// 116.220 us; speedup vs baseline: 1.3579x; 1.0502x over previous
//
#include <hip/hip_runtime.h>
#include <hip/hip_bf16.h>

// ChannelDeAttention: B=64,S=512,C=256,H=128,P=512
// bf16 MFMA (16x16x32), fp32 accum. 6 launches. XOR-swizzled LDS.
// R13 = R10 geometry (8-wave, BM128xBN256 proj / 256x128 chain, BK=64) with a
// 3-stage LDS pipeline: prefetch distance 2, counted s_waitcnt vmcnt(N) + raw
// s_barrier (never drain to 0 mid-loop). WVO fusion kept.

typedef __attribute__((ext_vector_type(8))) short bf16x8;
typedef __attribute__((ext_vector_type(4))) float f32x4;
typedef __attribute__((ext_vector_type(8))) unsigned short ushort8;

typedef __attribute__((address_space(1))) void* as1vp;
typedef __attribute__((address_space(3))) void* as3vp;

__device__ __forceinline__ void gl2lds16(const void* g, void* l) {
  __builtin_amdgcn_global_load_lds((as1vp)(void*)g, (as3vp)l, 16, 0, 0);
}

__device__ __forceinline__ float bf2f(unsigned short u) {
  union { unsigned int i; float f; } v; v.i = ((unsigned int)u) << 16; return v.f;
}
__device__ __forceinline__ unsigned short f2bf(float f) {
  union { float f; unsigned int i; } v; v.f = f;
  unsigned int r = v.i + 0x7FFFu + ((v.i >> 16) & 1u);
  return (unsigned short)(r >> 16);
}
__device__ __forceinline__ unsigned long long pack4bf(float a, float b, float c, float d) {
  return (unsigned long long)f2bf(a) | ((unsigned long long)f2bf(b) << 16) |
         ((unsigned long long)f2bf(c) << 32) | ((unsigned long long)f2bf(d) << 48);
}

// ------- transposes (x + 5 weight mats) + plain wv cast, one launch -----------------
__global__ void __launch_bounds__(256) tcast_all(
    const float* __restrict__ x,
    const float* __restrict__ wq1, const float* __restrict__ wk1,
    const float* __restrict__ wq2, const float* __restrict__ wk2,
    const float* __restrict__ wq3, const float* __restrict__ wk3,
    const float* __restrict__ wv, const float* __restrict__ wo,
    unsigned short* __restrict__ XT,
    unsigned short* __restrict__ W1, unsigned short* __restrict__ W2,
    unsigned short* __restrict__ W3, unsigned short* __restrict__ WVNT,
    unsigned short* __restrict__ WOT) {
  const int bid = blockIdx.x;
  const int t = threadIdx.x;
  if (bid >= 2168) {  // plain-cast wv to bf16 row-major (coalesced)
    long i0 = (long)(bid - 2168) * 2048 + t * 8;
    f32x4 a = *(const f32x4*)(wv + i0);
    f32x4 b = *(const f32x4*)(wv + i0 + 4);
    ushort8 o;
#pragma unroll
    for (int j = 0; j < 4; ++j) { o[j] = f2bf(a[j]); o[4 + j] = f2bf(b[j]); }
    *(ushort8*)(WVNT + i0) = o;
    return;
  }
  __shared__ float lds[64][68];
  const float* S; unsigned short* D; int R, Cc, r0, c0, rowoff = 0;
  if (bid < 2048) {
    int bz = bid >> 5, i = bid & 31;
    S = x + (long)bz * 131072; D = XT + (long)bz * 131072;
    R = 512; Cc = 256; r0 = (i & 7) * 64; c0 = (i >> 3) * 64;
  } else {
    int wb = bid - 2048;
    if (wb < 32) {
      int m = wb >> 4, i = wb & 15;
      S = m ? wk1 : wq1; D = W1; R = 512; Cc = 128;
      r0 = (i & 7) * 64; c0 = (i >> 3) * 64; rowoff = m * 128;
    } else if (wb < 48) {
      int m = (wb - 32) >> 3, i = (wb - 32) & 7;
      S = m ? wk2 : wq2; D = W2; R = 256; Cc = 128;
      r0 = (i & 3) * 64; c0 = (i >> 2) * 64; rowoff = m * 128;
    } else if (wb < 56) {
      int m = (wb - 48) >> 2, i = (wb - 48) & 3;
      S = m ? wk3 : wq3; D = W3; R = 128; Cc = 128;
      r0 = (i & 1) * 64; c0 = (i >> 1) * 64; rowoff = m * 128;
    } else {
      int i = wb - 56; S = wo; D = WOT; R = 512; Cc = 512;
      r0 = (i & 7) * 64; c0 = (i >> 3) * 64;
    }
  }
  {
    const int row = t >> 2, cq = (t & 3) * 16;
    const float* Sp = S + (long)(r0 + row) * Cc + c0 + cq;
#pragma unroll
    for (int j = 0; j < 4; ++j)
      *(f32x4*)&lds[row][cq + j * 4] = *(const f32x4*)(Sp + j * 4);
  }
  __syncthreads();
  {
    const int rq = (t & 15) * 4, ccb = t >> 4;
#pragma unroll
    for (int j = 0; j < 4; ++j) {
      int cc = ccb + j * 16;
      *(unsigned long long*)(D + (long)(c0 + cc + rowoff) * R + r0 + rq) =
          pack4bf(lds[rq][cc], lds[rq + 1][cc], lds[rq + 2][cc], lds[rq + 3][cc]);
    }
  }
}

// ------- fused Q/K projections + WVOT SQ-gemm blocks + BVO blocks, one launch -------
// grid (1,2,458): z<448 proj; z in [448,456) WVOT; z>=456 BVO.
// 3-stage pipeline: per-buf proj 48KB (A[128][64]sw 16K + B[256][64]sw 32K),
// WVOT 32KB. Counted vmcnt, raw s_barrier.
__global__ void __launch_bounds__(512) proj_all8(
    const unsigned short* __restrict__ XT,
    const unsigned short* __restrict__ W1, const unsigned short* __restrict__ W2,
    const unsigned short* __restrict__ W3,
    const unsigned short* __restrict__ WOT, const unsigned short* __restrict__ WVNT,
    unsigned short* __restrict__ WVOT, float* __restrict__ BVO,
    const float* __restrict__ bv,
    unsigned short* __restrict__ Q1, unsigned short* __restrict__ Q2,
    unsigned short* __restrict__ Q3,
    const float* __restrict__ bq1, const float* __restrict__ bk1,
    const float* __restrict__ bq2, const float* __restrict__ bk2,
    const float* __restrict__ bq3, const float* __restrict__ bk3) {
  extern __shared__ char smem[];
  const int z = blockIdx.z;
  const int t = threadIdx.x, lane = t & 63, wid = t >> 6;

  if (z >= 456) {  // ---- BVO[p] = sum_s bv[s] * WOT[p][s]
    int p0 = ((z - 456) * 2 + blockIdx.y) * 128 + wid * 16;
    f32x4 b0 = *(const f32x4*)(bv + lane * 8);
    f32x4 b1 = *(const f32x4*)(bv + lane * 8 + 4);
#pragma unroll
    for (int i = 0; i < 16; ++i) {
      int p = p0 + i;
      bf16x8 wrow = *(const bf16x8*)(WOT + (long)p * 512 + lane * 8);
      float s = 0.0f;
#pragma unroll
      for (int j = 0; j < 4; ++j) {
        s += b0[j] * bf2f((unsigned short)wrow[j]);
        s += b1[j] * bf2f((unsigned short)wrow[4 + j]);
      }
#pragma unroll
      for (int off = 1; off < 64; off <<= 1) s += __shfl_xor(s, off, 64);
      if (lane == 0) BVO[p] = s;
    }
    return;
  }

  const int srow = t >> 3, ssl = t & 7;

  if (z >= 448) {  // ---- WVOT[p][s] = sum_t WOT[p][t]*wv[s][t], SQ128, 3-stage
    const int w = (z - 448) * 2 + blockIdx.y;
    const int m0 = (w >> 2) * 128, n0 = (w & 3) * 128;
    const unsigned short* Ab = WOT + (long)m0 * 512;
    const unsigned short* Bb = WVNT + (long)n0 * 512;
    const int wmb = (wid >> 2) * 64, wnb = (wid & 3) * 32;
    f32x4 acc[4][2] = {};
    auto stageS = [&](int buf, int k0) {  // 4 loads/thread
      char* s = smem + buf * 32768;
#pragma unroll
      for (int i = 0; i < 2; ++i) {
        int row = i * 64 + srow;
        gl2lds16(Ab + (long)row * 512 + k0 + (ssl ^ (row & 7)) * 8, s + i * 8192 + t * 16);
        gl2lds16(Bb + (long)row * 512 + k0 + (ssl ^ (row & 7)) * 8, s + 16384 + i * 8192 + t * 16);
      }
    };
    stageS(0, 0);
    stageS(1, 64);
    for (int j = 0; j < 8; ++j) {
      if (j < 7) asm volatile("s_waitcnt vmcnt(4)" ::: "memory");
      else       asm volatile("s_waitcnt vmcnt(0)" ::: "memory");
      __builtin_amdgcn_s_barrier();
      if (j + 2 < 8) stageS((j + 2) % 3, (j + 2) * 64);
      const char* s = smem + (j % 3) * 32768;
#pragma unroll
      for (int kk = 0; kk < 2; ++kk) {
        const int slot = kk * 4 + (lane >> 4);
        bf16x8 af[4], bfr[2];
#pragma unroll
        for (int mi = 0; mi < 4; ++mi) {
          int row = wmb + mi * 16 + (lane & 15);
          af[mi] = *(const bf16x8*)(s + row * 128 + 16 * (slot ^ (row & 7)));
        }
#pragma unroll
        for (int ni = 0; ni < 2; ++ni) {
          int row = wnb + ni * 16 + (lane & 15);
          bfr[ni] = *(const bf16x8*)(s + 16384 + row * 128 + 16 * (slot ^ (row & 7)));
        }
#pragma unroll
        for (int mi = 0; mi < 4; ++mi)
#pragma unroll
          for (int ni = 0; ni < 2; ++ni)
            acc[mi][ni] = __builtin_amdgcn_mfma_f32_16x16x32_bf16(af[mi], bfr[ni], acc[mi][ni], 0, 0, 0);
      }
    }
#pragma unroll
    for (int ni = 0; ni < 2; ++ni) {
      int col = n0 + wnb + ni * 16 + (lane & 15);
#pragma unroll
      for (int mi = 0; mi < 4; ++mi) {
        int rowb = m0 + wmb + mi * 16 + (lane >> 4) * 4;
#pragma unroll
        for (int r = 0; r < 4; ++r)
          WVOT[(long)(rowb + r) * 512 + col] = f2bf(acc[mi][ni][r]);
      }
    }
    return;
  }

  // ---- normal proj path ----
  const unsigned short* Ab; const unsigned short* Bw; unsigned short* O;
  const float *bq, *bk; int K;
  if (z < 64) {
    K = 512; Bw = W1; O = Q1 + (long)z * 65536; bq = bq1; bk = bk1;
    Ab = XT + (long)z * 131072;
  } else if (z < 192) {
    int u = z - 64; K = 256; Bw = W2; O = Q2 + (long)u * 65536; bq = bq2; bk = bk2;
    Ab = XT + (long)(u >> 1) * 131072 + (u & 1) * 256;
  } else {
    int u = z - 192; K = 128; Bw = W3; O = Q3 + (long)u * 65536; bq = bq3; bk = bk3;
    Ab = XT + (long)(u >> 2) * 131072 + (u & 3) * 128;
  }
  const int wmb = (wid >> 2) * 64, wnb = (wid & 3) * 64;
  const int m0 = blockIdx.y * 128;
  Ab += (long)m0 * 512;

  auto stage = [&](int buf, int k0) {  // 6 loads/thread
    char* s = smem + buf * 49152;
#pragma unroll
    for (int i = 0; i < 2; ++i) {
      int row = i * 64 + srow;
      gl2lds16(Ab + (long)row * 512 + k0 + (ssl ^ (row & 7)) * 8, s + i * 8192 + t * 16);
    }
#pragma unroll
    for (int i = 0; i < 4; ++i) {
      int row = i * 64 + srow;
      gl2lds16(Bw + (long)row * K + k0 + (ssl ^ (row & 7)) * 8, s + 16384 + i * 8192 + t * 16);
    }
  };

  f32x4 acc[4][4] = {};
  const int nst = K >> 6;
  stage(0, 0);
  stage(1, 64);  // K>=128 always
  for (int j = 0; j < nst; ++j) {
    if (j + 1 < nst) asm volatile("s_waitcnt vmcnt(6)" ::: "memory");
    else             asm volatile("s_waitcnt vmcnt(0)" ::: "memory");
    __builtin_amdgcn_s_barrier();
    if (j + 2 < nst) stage((j + 2) % 3, (j + 2) * 64);
    const char* s = smem + (j % 3) * 49152;
#pragma unroll
    for (int kk = 0; kk < 2; ++kk) {
      const int slot = kk * 4 + (lane >> 4);
      bf16x8 af[4], bfr[4];
#pragma unroll
      for (int mi = 0; mi < 4; ++mi) {
        int row = wmb + mi * 16 + (lane & 15);
        af[mi] = *(const bf16x8*)(s + row * 128 + 16 * (slot ^ (row & 7)));
      }
#pragma unroll
      for (int ni = 0; ni < 4; ++ni) {
        int row = wnb + ni * 16 + (lane & 15);
        bfr[ni] = *(const bf16x8*)(s + 16384 + row * 128 + 16 * (slot ^ (row & 7)));
      }
#pragma unroll
      for (int mi = 0; mi < 4; ++mi)
#pragma unroll
        for (int ni = 0; ni < 4; ++ni)
          acc[mi][ni] = __builtin_amdgcn_mfma_f32_16x16x32_bf16(af[mi], bfr[ni], acc[mi][ni], 0, 0, 0);
    }
  }
#pragma unroll
  for (int ni = 0; ni < 4; ++ni) {
    int colL = wnb + ni * 16 + (lane & 15);
    float bv_ = (colL < 128) ? bq[colL] : bk[colL - 128];
#pragma unroll
    for (int mi = 0; mi < 4; ++mi) {
      int rowb = m0 + wmb + mi * 16 + (lane >> 4) * 4;
#pragma unroll
      for (int r = 0; r < 4; ++r)
        O[(long)(rowb + r) * 256 + colL] = f2bf(acc[mi][ni][r] + bv_);
    }
  }
}

// ------- pass A: scales 2+3 scores + softmax + sub-batch mean (unchanged) -----------
__global__ void __launch_bounds__(256) scores_mean(
    const unsigned short* __restrict__ QK2, const unsigned short* __restrict__ QK3,
    unsigned short* __restrict__ A2P, unsigned short* __restrict__ A3P) {
  __shared__ unsigned short Qs[64 * 64];
  __shared__ unsigned short Ks[256 * 64];
  const int bid = blockIdx.x;
  const unsigned short* QK; unsigned short* Aout; int NS, b, m0idx;
  if (bid < 256) { NS = 4; b = bid >> 2; m0idx = bid & 3; QK = QK3; Aout = A3P; }
  else { int u = bid - 256; NS = 2; b = u >> 2; m0idx = u & 3; QK = QK2; Aout = A2P; }
  const int m0 = m0idx * 64;
  const int t = threadIdx.x, lane = t & 63, w = t >> 6;
  const int r8 = t >> 3, sl = t & 7;
  const float sc = 0.088388347648318447f;
  const float invNS = 1.0f / NS;
  f32x4 avg[16] = {};
  for (int h = 0; h < NS; ++h) {
    const unsigned short* base = QK + ((long)(b * NS + h) << 16);
    f32x4 acc[16] = {};
    for (int kc = 0; kc < 2; ++kc) {
#pragma unroll
      for (int i = 0; i < 2; ++i) {
        int row = i * 32 + r8;
        gl2lds16(base + (long)(m0 + row) * 256 + kc * 64 + (sl ^ (row & 7)) * 8,
                 (char*)Qs + i * 4096 + t * 16);
      }
#pragma unroll
      for (int i = 0; i < 8; ++i) {
        int row = i * 32 + r8;
        gl2lds16(base + (long)row * 256 + 128 + kc * 64 + (sl ^ (row & 7)) * 8,
                 (char*)Ks + i * 4096 + t * 16);
      }
      __syncthreads();
#pragma unroll
      for (int kk = 0; kk < 2; ++kk) {
        const int qrow = w * 16 + (lane & 15);
        const int slot = kk * 4 + (lane >> 4);
        bf16x8 qf = *(const bf16x8*)((char*)Qs + qrow * 128 + 16 * (slot ^ (qrow & 7)));
#pragma unroll
        for (int ni = 0; ni < 16; ++ni) {
          int krow = ni * 16 + (lane & 15);
          bf16x8 kf = *(const bf16x8*)((char*)Ks + krow * 128 + 16 * (slot ^ (krow & 7)));
          acc[ni] = __builtin_amdgcn_mfma_f32_16x16x32_bf16(qf, kf, acc[ni], 0, 0, 0);
        }
      }
      __syncthreads();
    }
#pragma unroll
    for (int r = 0; r < 4; ++r) {
      float mx = -1e30f;
#pragma unroll
      for (int ni = 0; ni < 16; ++ni) mx = fmaxf(mx, acc[ni][r]);
#pragma unroll
      for (int off = 1; off < 16; off <<= 1) mx = fmaxf(mx, __shfl_xor(mx, off, 64));
      float s = 0.0f;
#pragma unroll
      for (int ni = 0; ni < 16; ++ni) {
        float p = __expf((acc[ni][r] - mx) * sc);
        acc[ni][r] = p;
        s += p;
      }
#pragma unroll
      for (int off = 1; off < 16; off <<= 1) s += __shfl_xor(s, off, 64);
      float f = invNS / s;
#pragma unroll
      for (int ni = 0; ni < 16; ++ni) avg[ni][r] += acc[ni][r] * f;
    }
  }
  unsigned short* Of = Aout + (((long)b * 4 + m0idx) * 256 + t) * 64;
#pragma unroll
  for (int r = 0; r < 4; ++r) {
    ushort8 lo, hi;
#pragma unroll
    for (int j = 0; j < 8; ++j) { lo[j] = f2bf(avg[j][r]); hi[j] = f2bf(avg[8 + j][r]); }
    *(ushort8*)(Of + r * 16) = lo;
    *(ushort8*)(Of + r * 16 + 8) = hi;
  }
}

// ------- pass B: scale1 scores + softmax + gate combine -> ATTN (unchanged) ---------
__global__ void __launch_bounds__(256) scores1_gate(
    const unsigned short* __restrict__ QK1, const unsigned short* __restrict__ A2P,
    const unsigned short* __restrict__ A3P, unsigned short* __restrict__ ATTN) {
  __shared__ unsigned short Qs[64 * 64];
  __shared__ unsigned short Ks[256 * 64];
  const int bid = blockIdx.x;
  const int b = bid >> 2, m0 = (bid & 3) * 64;
  const unsigned short* base = QK1 + ((long)b << 16);
  const int t = threadIdx.x, lane = t & 63, w = t >> 6;
  const int r8 = t >> 3, sl = t & 7;
  f32x4 acc[16] = {};
  for (int kc = 0; kc < 2; ++kc) {
#pragma unroll
    for (int i = 0; i < 2; ++i) {
      int row = i * 32 + r8;
      gl2lds16(base + (long)(m0 + row) * 256 + kc * 64 + (sl ^ (row & 7)) * 8,
               (char*)Qs + i * 4096 + t * 16);
    }
#pragma unroll
    for (int i = 0; i < 8; ++i) {
      int row = i * 32 + r8;
      gl2lds16(base + (long)row * 256 + 128 + kc * 64 + (sl ^ (row & 7)) * 8,
               (char*)Ks + i * 4096 + t * 16);
    }
    __syncthreads();
#pragma unroll
    for (int kk = 0; kk < 2; ++kk) {
      const int qrow = w * 16 + (lane & 15);
      const int slot = kk * 4 + (lane >> 4);
      bf16x8 qf = *(const bf16x8*)((char*)Qs + qrow * 128 + 16 * (slot ^ (qrow & 7)));
#pragma unroll
      for (int ni = 0; ni < 16; ++ni) {
        int krow = ni * 16 + (lane & 15);
        bf16x8 kf = *(const bf16x8*)((char*)Ks + krow * 128 + 16 * (slot ^ (krow & 7)));
        acc[ni] = __builtin_amdgcn_mfma_f32_16x16x32_bf16(qf, kf, acc[ni], 0, 0, 0);
      }
    }
    __syncthreads();
  }
  const float sc = 0.088388347648318447f;
#pragma unroll
  for (int r = 0; r < 4; ++r) {
    float mx = -1e30f;
#pragma unroll
    for (int ni = 0; ni < 16; ++ni) mx = fmaxf(mx, acc[ni][r]);
#pragma unroll
    for (int off = 1; off < 16; off <<= 1) mx = fmaxf(mx, __shfl_xor(mx, off, 64));
    float s = 0.0f;
#pragma unroll
    for (int ni = 0; ni < 16; ++ni) {
      float p = __expf((acc[ni][r] - mx) * sc);
      acc[ni][r] = p;
      s += p;
    }
#pragma unroll
    for (int off = 1; off < 16; off <<= 1) s += __shfl_xor(s, off, 64);
    float inv = 1.0f / s;
    long fidx = ((long)bid * 256 + t) * 64 + r * 16;
    ushort8 a2l = *(const ushort8*)(A2P + fidx);
    ushort8 a2h = *(const ushort8*)(A2P + fidx + 8);
    ushort8 a3l = *(const ushort8*)(A3P + fidx);
    ushort8 a3h = *(const ushort8*)(A3P + fidx + 8);
    int row = m0 + w * 16 + (lane >> 4) * 4 + r;
    long roff = ((long)b << 16) + (long)row * 256 + (lane & 15);
#pragma unroll
    for (int j = 0; j < 8; ++j) {
      float A1 = acc[j][r] * inv;
      float A2 = bf2f(a2l[j]), A3 = bf2f(a3l[j]);
      float m = fmaxf(A1, fmaxf(A2, A3));
      float e1 = __expf(A1 - m), e2 = __expf(A2 - m), e3 = __expf(A3 - m);
      ATTN[roff + j * 16] = f2bf((A1 * e1 + A2 * e2 + A3 * e3) / (e1 + e2 + e3));
    }
#pragma unroll
    for (int j = 0; j < 8; ++j) {
      float A1 = acc[8 + j][r] * inv;
      float A2 = bf2f(a2h[j]), A3 = bf2f(a3h[j]);
      float m = fmaxf(A1, fmaxf(A2, A3));
      float e1 = __expf(A1 - m), e2 = __expf(A2 - m), e3 = __expf(A3 - m);
      ATTN[roff + (8 + j) * 16] = f2bf((A1 * e1 + A2 * e2 + A3 * e3) / (e1 + e2 + e3));
    }
  }
}

// ------- 8-wave TALL(256x128) NT GEMM, 3-stage pipeline, counted vmcnt --------------
// BIASMODE: 0 none, 2 per-row. Out row-major [M][ldo].
template <int F32OUT, int BIASMODE>
__global__ void __launch_bounds__(512) gemm8(
    const unsigned short* __restrict__ A, const unsigned short* __restrict__ B,
    void* __restrict__ OutV, const float* __restrict__ bias,
    int lda, int ldb, int K, long astr, long bstr, long ostr, int ldo) {
  extern __shared__ char smem[];  // per buf 48K: A [256][64]sw + B [128][64]sw
  const int t = threadIdx.x, lane = t & 63, wid = t >> 6;
  const int wmb = (wid >> 1) * 64, wnb = (wid & 1) * 64;
  const int m0 = blockIdx.y * 256, n0 = blockIdx.x * 128;
  const int bz = blockIdx.z;
  const unsigned short* Ab = A + (long)bz * astr + (long)m0 * lda;
  const unsigned short* Bb = B + (long)bz * bstr + (long)n0 * ldb;
  const int srow = t >> 3, ssl = t & 7;

  auto stage = [&](int buf, int k0) {  // 6 loads/thread
    char* s = smem + buf * 49152;
#pragma unroll
    for (int i = 0; i < 4; ++i) {
      int row = i * 64 + srow;
      gl2lds16(Ab + (long)row * lda + k0 + (ssl ^ (row & 7)) * 8, s + i * 8192 + t * 16);
    }
#pragma unroll
    for (int i = 0; i < 2; ++i) {
      int row = i * 64 + srow;
      gl2lds16(Bb + (long)row * ldb + k0 + (ssl ^ (row & 7)) * 8,
               s + 32768 + i * 8192 + t * 16);
    }
  };

  f32x4 acc[4][4] = {};
  const int nst = K >> 6;
  stage(0, 0);
  stage(1, 64);  // K>=256 in all uses
  for (int j = 0; j < nst; ++j) {
    if (j + 1 < nst) asm volatile("s_waitcnt vmcnt(6)" ::: "memory");
    else             asm volatile("s_waitcnt vmcnt(0)" ::: "memory");
    __builtin_amdgcn_s_barrier();
    if (j + 2 < nst) stage((j + 2) % 3, (j + 2) * 64);
    const char* s = smem + (j % 3) * 49152;
#pragma unroll
    for (int kk = 0; kk < 2; ++kk) {
      const int slot = kk * 4 + (lane >> 4);
      bf16x8 af[4], bfr[4];
#pragma unroll
      for (int mi = 0; mi < 4; ++mi) {
        int row = wmb + mi * 16 + (lane & 15);
        af[mi] = *(const bf16x8*)(s + row * 128 + 16 * (slot ^ (row & 7)));
      }
#pragma unroll
      for (int ni = 0; ni < 4; ++ni) {
        int row = wnb + ni * 16 + (lane & 15);
        bfr[ni] = *(const bf16x8*)(s + 32768 + row * 128 + 16 * (slot ^ (row & 7)));
      }
#pragma unroll
      for (int mi = 0; mi < 4; ++mi)
#pragma unroll
        for (int ni = 0; ni < 4; ++ni)
          acc[mi][ni] = __builtin_amdgcn_mfma_f32_16x16x32_bf16(af[mi], bfr[ni], acc[mi][ni], 0, 0, 0);
    }
  }
#pragma unroll
  for (int mi = 0; mi < 4; ++mi) {
    int rowb = m0 + wmb + mi * 16 + (lane >> 4) * 4;
    float rb[4];
#pragma unroll
    for (int r = 0; r < 4; ++r) rb[r] = (BIASMODE == 2) ? bias[rowb + r] : 0.0f;
#pragma unroll
    for (int ni = 0; ni < 4; ++ni) {
      int col = n0 + wnb + ni * 16 + (lane & 15);
#pragma unroll
      for (int r = 0; r < 4; ++r) {
        float v = acc[mi][ni][r] + rb[r];
        if constexpr (F32OUT)
          ((float*)OutV)[(long)bz * ostr + (long)(rowb + r) * ldo + col] = v;
        else
          ((unsigned short*)OutV)[(long)bz * ostr + (long)(rowb + r) * ldo + col] = f2bf(v);
      }
    }
  }
}

// ------------------------------------------------------------------------------------
extern "C" void kernel_launch(void* const* d_in, const int* in_sizes, int n_in,
                              void* d_out, int out_size, void* d_ws, size_t ws_size,
                              hipStream_t stream) {
  (void)in_sizes; (void)n_in; (void)out_size; (void)ws_size;
  const float* x   = (const float*)d_in[0];
  const float* wq1 = (const float*)d_in[1];
  const float* bq1 = (const float*)d_in[2];
  const float* wk1 = (const float*)d_in[3];
  const float* bk1 = (const float*)d_in[4];
  const float* wq2 = (const float*)d_in[5];
  const float* bq2 = (const float*)d_in[6];
  const float* wk2 = (const float*)d_in[7];
  const float* bk2 = (const float*)d_in[8];
  const float* wq3 = (const float*)d_in[9];
  const float* bq3 = (const float*)d_in[10];
  const float* wk3 = (const float*)d_in[11];
  const float* bk3 = (const float*)d_in[12];
  const float* wv  = (const float*)d_in[13];
  const float* bv  = (const float*)d_in[14];
  const float* wo  = (const float*)d_in[15];
  const float* bo  = (const float*)d_in[16];
  char* ws = (char*)d_ws;

  // workspace layout (bytes), peak ~94.4 MB
  unsigned short* XT   = (unsigned short*)(ws + 0);         // [64][256][512] 16.8MB
  unsigned short* WQK1 = (unsigned short*)(ws + 16777216);  // [256][512]
  unsigned short* WQK2 = (unsigned short*)(ws + 17039360);  // [256][256]
  unsigned short* WQK3 = (unsigned short*)(ws + 17170432);  // [256][128]
  unsigned short* WOT  = (unsigned short*)(ws + 17235968);  // [512][512] wo^T
  unsigned short* WVNT = (unsigned short*)(ws + 17760256);  // [512][512] wv row-major
  unsigned short* WVOT = (unsigned short*)(ws + 18284544);  // [512][512] (wv@wo)^T
  float*          BVO  = (float*)(ws + 18808832);           // [512] bv@wo
  unsigned short* QK1  = (unsigned short*)(ws + 18876416);  // [64][256][256]
  unsigned short* QK2  = (unsigned short*)(ws + 27265024);  // [128][256][256]
  unsigned short* QK3  = (unsigned short*)(ws + 44042240);  // [256][256][256]
  unsigned short* A2P  = (unsigned short*)(ws + 77596672);  // fragment layout
  unsigned short* A3P  = (unsigned short*)(ws + 85985280);  // fragment layout
  unsigned short* ATTN = (unsigned short*)(ws + 44042240);  // over dead QK3
  unsigned short* XVT  = (unsigned short*)(ws + 18876416);  // over dead QK1/QK2

  tcast_all<<<dim3(2296), dim3(256), 0, stream>>>(
      x, wq1, wk1, wq2, wk2, wq3, wk3, wv, wo,
      XT, WQK1, WQK2, WQK3, WVNT, WOT);

  proj_all8<<<dim3(1, 2, 458), dim3(512), 147456, stream>>>(
      XT, WQK1, WQK2, WQK3, WOT, WVNT, WVOT, BVO, bv,
      QK1, QK2, QK3, bq1, bk1, bq2, bk2, bq3, bk3);

  scores_mean<<<dim3(512), dim3(256), 0, stream>>>(QK2, QK3, A2P, A3P);
  scores1_gate<<<dim3(256), dim3(256), 0, stream>>>(QK1, A2P, A3P, ATTN);

  // XVT[b][p][d] = sum_s WVOT[p][s]*XT[b][d][s] + BVO[p]   (row-bias)
  gemm8<0, 2><<<dim3(2, 2, 64), dim3(512), 147456, stream>>>(
      WVOT, XT, XVT, BVO, 512, 512, 512, 0, 131072, 131072, 256);
  // out[b][p][c] = sum_d XVT[b][p][d]*ATTN[b][c][d] + bo[p] (row-bias, fp32)
  gemm8<1, 2><<<dim3(2, 2, 64), dim3(512), 147456, stream>>>(
      XVT, ATTN, d_out, bo, 256, 256, 256, 131072, 65536, 131072, 256);
}

// Round 14
// 114.734 us; speedup vs baseline: 1.3755x; 1.0130x over previous
//
#include <hip/hip_runtime.h>
#include <hip/hip_bf16.h>

// ChannelDeAttention: B=64,S=512,C=256,H=128,P=512
// bf16 MFMA (16x16x32), fp32 accum. 6 launches. XOR-swizzled LDS.
// R14: proj -> 8 waves x (64x128) wave-tile, BM=256xBN=256 per sub-batch,
// 2-buffer issue-early dbuf (64KB stages, 128KB LDS). LDS-reads/MFMA cut 25%
// -> MFMA-bound inner loop. Chain GEMMs keep R13 3-stage counted-vmcnt.

typedef __attribute__((ext_vector_type(8))) short bf16x8;
typedef __attribute__((ext_vector_type(4))) float f32x4;
typedef __attribute__((ext_vector_type(8))) unsigned short ushort8;

typedef __attribute__((address_space(1))) void* as1vp;
typedef __attribute__((address_space(3))) void* as3vp;

__device__ __forceinline__ void gl2lds16(const void* g, void* l) {
  __builtin_amdgcn_global_load_lds((as1vp)(void*)g, (as3vp)l, 16, 0, 0);
}

__device__ __forceinline__ float bf2f(unsigned short u) {
  union { unsigned int i; float f; } v; v.i = ((unsigned int)u) << 16; return v.f;
}
__device__ __forceinline__ unsigned short f2bf(float f) {
  union { float f; unsigned int i; } v; v.f = f;
  unsigned int r = v.i + 0x7FFFu + ((v.i >> 16) & 1u);
  return (unsigned short)(r >> 16);
}
__device__ __forceinline__ unsigned long long pack4bf(float a, float b, float c, float d) {
  return (unsigned long long)f2bf(a) | ((unsigned long long)f2bf(b) << 16) |
         ((unsigned long long)f2bf(c) << 32) | ((unsigned long long)f2bf(d) << 48);
}

// ------- transposes (x + 5 weight mats) + plain wv cast, one launch -----------------
__global__ void __launch_bounds__(256) tcast_all(
    const float* __restrict__ x,
    const float* __restrict__ wq1, const float* __restrict__ wk1,
    const float* __restrict__ wq2, const float* __restrict__ wk2,
    const float* __restrict__ wq3, const float* __restrict__ wk3,
    const float* __restrict__ wv, const float* __restrict__ wo,
    unsigned short* __restrict__ XT,
    unsigned short* __restrict__ W1, unsigned short* __restrict__ W2,
    unsigned short* __restrict__ W3, unsigned short* __restrict__ WVNT,
    unsigned short* __restrict__ WOT) {
  const int bid = blockIdx.x;
  const int t = threadIdx.x;
  if (bid >= 2168) {  // plain-cast wv to bf16 row-major (coalesced)
    long i0 = (long)(bid - 2168) * 2048 + t * 8;
    f32x4 a = *(const f32x4*)(wv + i0);
    f32x4 b = *(const f32x4*)(wv + i0 + 4);
    ushort8 o;
#pragma unroll
    for (int j = 0; j < 4; ++j) { o[j] = f2bf(a[j]); o[4 + j] = f2bf(b[j]); }
    *(ushort8*)(WVNT + i0) = o;
    return;
  }
  __shared__ float lds[64][68];
  const float* S; unsigned short* D; int R, Cc, r0, c0, rowoff = 0;
  if (bid < 2048) {
    int bz = bid >> 5, i = bid & 31;
    S = x + (long)bz * 131072; D = XT + (long)bz * 131072;
    R = 512; Cc = 256; r0 = (i & 7) * 64; c0 = (i >> 3) * 64;
  } else {
    int wb = bid - 2048;
    if (wb < 32) {
      int m = wb >> 4, i = wb & 15;
      S = m ? wk1 : wq1; D = W1; R = 512; Cc = 128;
      r0 = (i & 7) * 64; c0 = (i >> 3) * 64; rowoff = m * 128;
    } else if (wb < 48) {
      int m = (wb - 32) >> 3, i = (wb - 32) & 7;
      S = m ? wk2 : wq2; D = W2; R = 256; Cc = 128;
      r0 = (i & 3) * 64; c0 = (i >> 2) * 64; rowoff = m * 128;
    } else if (wb < 56) {
      int m = (wb - 48) >> 2, i = (wb - 48) & 3;
      S = m ? wk3 : wq3; D = W3; R = 128; Cc = 128;
      r0 = (i & 1) * 64; c0 = (i >> 1) * 64; rowoff = m * 128;
    } else {
      int i = wb - 56; S = wo; D = WOT; R = 512; Cc = 512;
      r0 = (i & 7) * 64; c0 = (i >> 3) * 64;
    }
  }
  {
    const int row = t >> 2, cq = (t & 3) * 16;
    const float* Sp = S + (long)(r0 + row) * Cc + c0 + cq;
#pragma unroll
    for (int j = 0; j < 4; ++j)
      *(f32x4*)&lds[row][cq + j * 4] = *(const f32x4*)(Sp + j * 4);
  }
  __syncthreads();
  {
    const int rq = (t & 15) * 4, ccb = t >> 4;
#pragma unroll
    for (int j = 0; j < 4; ++j) {
      int cc = ccb + j * 16;
      *(unsigned long long*)(D + (long)(c0 + cc + rowoff) * R + r0 + rq) =
          pack4bf(lds[rq][cc], lds[rq + 1][cc], lds[rq + 2][cc], lds[rq + 3][cc]);
    }
  }
}

// ------- fused Q/K projections + WVOT SQ-gemm blocks + BVO blocks, one launch -------
// grid (1,1,468): z<448 proj (BM=256xBN=256, 64x128 wave-tiles, 2-buf dbuf);
// z in [448,464) WVOT (SQ128, 3-stage); z>=464 BVO.
__global__ void __launch_bounds__(512) proj_all8(
    const unsigned short* __restrict__ XT,
    const unsigned short* __restrict__ W1, const unsigned short* __restrict__ W2,
    const unsigned short* __restrict__ W3,
    const unsigned short* __restrict__ WOT, const unsigned short* __restrict__ WVNT,
    unsigned short* __restrict__ WVOT, float* __restrict__ BVO,
    const float* __restrict__ bv,
    unsigned short* __restrict__ Q1, unsigned short* __restrict__ Q2,
    unsigned short* __restrict__ Q3,
    const float* __restrict__ bq1, const float* __restrict__ bk1,
    const float* __restrict__ bq2, const float* __restrict__ bk2,
    const float* __restrict__ bq3, const float* __restrict__ bk3) {
  extern __shared__ char smem[];
  const int z = blockIdx.z;
  const int t = threadIdx.x, lane = t & 63, wid = t >> 6;

  if (z >= 464) {  // ---- BVO[p] = sum_s bv[s] * WOT[p][s]
    int p0 = (z - 464) * 128 + wid * 16;
    f32x4 b0 = *(const f32x4*)(bv + lane * 8);
    f32x4 b1 = *(const f32x4*)(bv + lane * 8 + 4);
#pragma unroll
    for (int i = 0; i < 16; ++i) {
      int p = p0 + i;
      bf16x8 wrow = *(const bf16x8*)(WOT + (long)p * 512 + lane * 8);
      float s = 0.0f;
#pragma unroll
      for (int j = 0; j < 4; ++j) {
        s += b0[j] * bf2f((unsigned short)wrow[j]);
        s += b1[j] * bf2f((unsigned short)wrow[4 + j]);
      }
#pragma unroll
      for (int off = 1; off < 64; off <<= 1) s += __shfl_xor(s, off, 64);
      if (lane == 0) BVO[p] = s;
    }
    return;
  }

  const int srow = t >> 3, ssl = t & 7;

  if (z >= 448) {  // ---- WVOT[p][s] = sum_t WOT[p][t]*wv[s][t], SQ128, 3-stage
    const int w = z - 448;
    const int m0 = (w >> 2) * 128, n0 = (w & 3) * 128;
    const unsigned short* Ab = WOT + (long)m0 * 512;
    const unsigned short* Bb = WVNT + (long)n0 * 512;
    const int wmb = (wid >> 2) * 64, wnb = (wid & 3) * 32;
    f32x4 acc[4][2] = {};
    auto stageS = [&](int buf, int k0) {  // 4 loads/thread
      char* s = smem + buf * 32768;
#pragma unroll
      for (int i = 0; i < 2; ++i) {
        int row = i * 64 + srow;
        gl2lds16(Ab + (long)row * 512 + k0 + (ssl ^ (row & 7)) * 8, s + i * 8192 + t * 16);
        gl2lds16(Bb + (long)row * 512 + k0 + (ssl ^ (row & 7)) * 8, s + 16384 + i * 8192 + t * 16);
      }
    };
    stageS(0, 0);
    stageS(1, 64);
    for (int j = 0; j < 8; ++j) {
      if (j < 7) asm volatile("s_waitcnt vmcnt(4)" ::: "memory");
      else       asm volatile("s_waitcnt vmcnt(0)" ::: "memory");
      __builtin_amdgcn_s_barrier();
      if (j + 2 < 8) stageS((j + 2) % 3, (j + 2) * 64);
      const char* s = smem + (j % 3) * 32768;
#pragma unroll
      for (int kk = 0; kk < 2; ++kk) {
        const int slot = kk * 4 + (lane >> 4);
        bf16x8 af[4], bfr[2];
#pragma unroll
        for (int mi = 0; mi < 4; ++mi) {
          int row = wmb + mi * 16 + (lane & 15);
          af[mi] = *(const bf16x8*)(s + row * 128 + 16 * (slot ^ (row & 7)));
        }
#pragma unroll
        for (int ni = 0; ni < 2; ++ni) {
          int row = wnb + ni * 16 + (lane & 15);
          bfr[ni] = *(const bf16x8*)(s + 16384 + row * 128 + 16 * (slot ^ (row & 7)));
        }
#pragma unroll
        for (int mi = 0; mi < 4; ++mi)
#pragma unroll
          for (int ni = 0; ni < 2; ++ni)
            acc[mi][ni] = __builtin_amdgcn_mfma_f32_16x16x32_bf16(af[mi], bfr[ni], acc[mi][ni], 0, 0, 0);
      }
    }
#pragma unroll
    for (int ni = 0; ni < 2; ++ni) {
      int col = n0 + wnb + ni * 16 + (lane & 15);
#pragma unroll
      for (int mi = 0; mi < 4; ++mi) {
        int rowb = m0 + wmb + mi * 16 + (lane >> 4) * 4;
#pragma unroll
        for (int r = 0; r < 4; ++r)
          WVOT[(long)(rowb + r) * 512 + col] = f2bf(acc[mi][ni][r]);
      }
    }
    return;
  }

  // ---- proj path: BM=256 (all channels) x BN=256 (q|k), 64x128 wave-tiles ----
  const unsigned short* Ab; const unsigned short* Bw; unsigned short* O;
  const float *bq, *bk; int K;
  if (z < 64) {
    K = 512; Bw = W1; O = Q1 + (long)z * 65536; bq = bq1; bk = bk1;
    Ab = XT + (long)z * 131072;
  } else if (z < 192) {
    int u = z - 64; K = 256; Bw = W2; O = Q2 + (long)u * 65536; bq = bq2; bk = bk2;
    Ab = XT + (long)(u >> 1) * 131072 + (u & 1) * 256;
  } else {
    int u = z - 192; K = 128; Bw = W3; O = Q3 + (long)u * 65536; bq = bq3; bk = bk3;
    Ab = XT + (long)(u >> 2) * 131072 + (u & 3) * 128;
  }
  const int wmb = (wid >> 1) * 64, wnb = (wid & 1) * 128;  // 4m x 2n waves

  auto stage = [&](int buf, int k0) {  // 8 loads/thread: A[256][64] + B[256][64]
    char* s = smem + buf * 65536;
#pragma unroll
    for (int i = 0; i < 4; ++i) {
      int row = i * 64 + srow;
      int sc = (ssl ^ (row & 7)) * 8;
      gl2lds16(Ab + (long)row * 512 + k0 + sc, s + i * 8192 + t * 16);
      gl2lds16(Bw + (long)row * K + k0 + sc, s + 32768 + i * 8192 + t * 16);
    }
  };

  f32x4 acc[4][8] = {};
  const int nst = K >> 6;
  stage(0, 0);
  __syncthreads();
  int cur = 0;
  for (int j = 0; j < nst; ++j) {
    if (j + 1 < nst) stage(cur ^ 1, (j + 1) * 64);
    const char* s = smem + cur * 65536;
#pragma unroll
    for (int kk = 0; kk < 2; ++kk) {
      const int slot = kk * 4 + (lane >> 4);
      bf16x8 af[4], bfr[8];
#pragma unroll
      for (int mi = 0; mi < 4; ++mi) {
        int row = wmb + mi * 16 + (lane & 15);
        af[mi] = *(const bf16x8*)(s + row * 128 + 16 * (slot ^ (row & 7)));
      }
#pragma unroll
      for (int ni = 0; ni < 8; ++ni) {
        int row = wnb + ni * 16 + (lane & 15);
        bfr[ni] = *(const bf16x8*)(s + 32768 + row * 128 + 16 * (slot ^ (row & 7)));
      }
#pragma unroll
      for (int mi = 0; mi < 4; ++mi)
#pragma unroll
        for (int ni = 0; ni < 8; ++ni)
          acc[mi][ni] = __builtin_amdgcn_mfma_f32_16x16x32_bf16(af[mi], bfr[ni], acc[mi][ni], 0, 0, 0);
    }
    __syncthreads();
    cur ^= 1;
  }
#pragma unroll
  for (int ni = 0; ni < 8; ++ni) {
    int colL = wnb + ni * 16 + (lane & 15);
    float bv_ = (colL < 128) ? bq[colL] : bk[colL - 128];
#pragma unroll
    for (int mi = 0; mi < 4; ++mi) {
      int rowb = wmb + mi * 16 + (lane >> 4) * 4;
#pragma unroll
      for (int r = 0; r < 4; ++r)
        O[(long)(rowb + r) * 256 + colL] = f2bf(acc[mi][ni][r] + bv_);
    }
  }
}

// ------- pass A: scales 2+3 scores + softmax + sub-batch mean (unchanged) -----------
__global__ void __launch_bounds__(256) scores_mean(
    const unsigned short* __restrict__ QK2, const unsigned short* __restrict__ QK3,
    unsigned short* __restrict__ A2P, unsigned short* __restrict__ A3P) {
  __shared__ unsigned short Qs[64 * 64];
  __shared__ unsigned short Ks[256 * 64];
  const int bid = blockIdx.x;
  const unsigned short* QK; unsigned short* Aout; int NS, b, m0idx;
  if (bid < 256) { NS = 4; b = bid >> 2; m0idx = bid & 3; QK = QK3; Aout = A3P; }
  else { int u = bid - 256; NS = 2; b = u >> 2; m0idx = u & 3; QK = QK2; Aout = A2P; }
  const int m0 = m0idx * 64;
  const int t = threadIdx.x, lane = t & 63, w = t >> 6;
  const int r8 = t >> 3, sl = t & 7;
  const float sc = 0.088388347648318447f;
  const float invNS = 1.0f / NS;
  f32x4 avg[16] = {};
  for (int h = 0; h < NS; ++h) {
    const unsigned short* base = QK + ((long)(b * NS + h) << 16);
    f32x4 acc[16] = {};
    for (int kc = 0; kc < 2; ++kc) {
#pragma unroll
      for (int i = 0; i < 2; ++i) {
        int row = i * 32 + r8;
        gl2lds16(base + (long)(m0 + row) * 256 + kc * 64 + (sl ^ (row & 7)) * 8,
                 (char*)Qs + i * 4096 + t * 16);
      }
#pragma unroll
      for (int i = 0; i < 8; ++i) {
        int row = i * 32 + r8;
        gl2lds16(base + (long)row * 256 + 128 + kc * 64 + (sl ^ (row & 7)) * 8,
                 (char*)Ks + i * 4096 + t * 16);
      }
      __syncthreads();
#pragma unroll
      for (int kk = 0; kk < 2; ++kk) {
        const int qrow = w * 16 + (lane & 15);
        const int slot = kk * 4 + (lane >> 4);
        bf16x8 qf = *(const bf16x8*)((char*)Qs + qrow * 128 + 16 * (slot ^ (qrow & 7)));
#pragma unroll
        for (int ni = 0; ni < 16; ++ni) {
          int krow = ni * 16 + (lane & 15);
          bf16x8 kf = *(const bf16x8*)((char*)Ks + krow * 128 + 16 * (slot ^ (krow & 7)));
          acc[ni] = __builtin_amdgcn_mfma_f32_16x16x32_bf16(qf, kf, acc[ni], 0, 0, 0);
        }
      }
      __syncthreads();
    }
#pragma unroll
    for (int r = 0; r < 4; ++r) {
      float mx = -1e30f;
#pragma unroll
      for (int ni = 0; ni < 16; ++ni) mx = fmaxf(mx, acc[ni][r]);
#pragma unroll
      for (int off = 1; off < 16; off <<= 1) mx = fmaxf(mx, __shfl_xor(mx, off, 64));
      float s = 0.0f;
#pragma unroll
      for (int ni = 0; ni < 16; ++ni) {
        float p = __expf((acc[ni][r] - mx) * sc);
        acc[ni][r] = p;
        s += p;
      }
#pragma unroll
      for (int off = 1; off < 16; off <<= 1) s += __shfl_xor(s, off, 64);
      float f = invNS / s;
#pragma unroll
      for (int ni = 0; ni < 16; ++ni) avg[ni][r] += acc[ni][r] * f;
    }
  }
  unsigned short* Of = Aout + (((long)b * 4 + m0idx) * 256 + t) * 64;
#pragma unroll
  for (int r = 0; r < 4; ++r) {
    ushort8 lo, hi;
#pragma unroll
    for (int j = 0; j < 8; ++j) { lo[j] = f2bf(avg[j][r]); hi[j] = f2bf(avg[8 + j][r]); }
    *(ushort8*)(Of + r * 16) = lo;
    *(ushort8*)(Of + r * 16 + 8) = hi;
  }
}

// ------- pass B: scale1 scores + softmax + gate combine -> ATTN (unchanged) ---------
__global__ void __launch_bounds__(256) scores1_gate(
    const unsigned short* __restrict__ QK1, const unsigned short* __restrict__ A2P,
    const unsigned short* __restrict__ A3P, unsigned short* __restrict__ ATTN) {
  __shared__ unsigned short Qs[64 * 64];
  __shared__ unsigned short Ks[256 * 64];
  const int bid = blockIdx.x;
  const int b = bid >> 2, m0 = (bid & 3) * 64;
  const unsigned short* base = QK1 + ((long)b << 16);
  const int t = threadIdx.x, lane = t & 63, w = t >> 6;
  const int r8 = t >> 3, sl = t & 7;
  f32x4 acc[16] = {};
  for (int kc = 0; kc < 2; ++kc) {
#pragma unroll
    for (int i = 0; i < 2; ++i) {
      int row = i * 32 + r8;
      gl2lds16(base + (long)(m0 + row) * 256 + kc * 64 + (sl ^ (row & 7)) * 8,
               (char*)Qs + i * 4096 + t * 16);
    }
#pragma unroll
    for (int i = 0; i < 8; ++i) {
      int row = i * 32 + r8;
      gl2lds16(base + (long)row * 256 + 128 + kc * 64 + (sl ^ (row & 7)) * 8,
               (char*)Ks + i * 4096 + t * 16);
    }
    __syncthreads();
#pragma unroll
    for (int kk = 0; kk < 2; ++kk) {
      const int qrow = w * 16 + (lane & 15);
      const int slot = kk * 4 + (lane >> 4);
      bf16x8 qf = *(const bf16x8*)((char*)Qs + qrow * 128 + 16 * (slot ^ (qrow & 7)));
#pragma unroll
      for (int ni = 0; ni < 16; ++ni) {
        int krow = ni * 16 + (lane & 15);
        bf16x8 kf = *(const bf16x8*)((char*)Ks + krow * 128 + 16 * (slot ^ (krow & 7)));
        acc[ni] = __builtin_amdgcn_mfma_f32_16x16x32_bf16(qf, kf, acc[ni], 0, 0, 0);
      }
    }
    __syncthreads();
  }
  const float sc = 0.088388347648318447f;
#pragma unroll
  for (int r = 0; r < 4; ++r) {
    float mx = -1e30f;
#pragma unroll
    for (int ni = 0; ni < 16; ++ni) mx = fmaxf(mx, acc[ni][r]);
#pragma unroll
    for (int off = 1; off < 16; off <<= 1) mx = fmaxf(mx, __shfl_xor(mx, off, 64));
    float s = 0.0f;
#pragma unroll
    for (int ni = 0; ni < 16; ++ni) {
      float p = __expf((acc[ni][r] - mx) * sc);
      acc[ni][r] = p;
      s += p;
    }
#pragma unroll
    for (int off = 1; off < 16; off <<= 1) s += __shfl_xor(s, off, 64);
    float inv = 1.0f / s;
    long fidx = ((long)bid * 256 + t) * 64 + r * 16;
    ushort8 a2l = *(const ushort8*)(A2P + fidx);
    ushort8 a2h = *(const ushort8*)(A2P + fidx + 8);
    ushort8 a3l = *(const ushort8*)(A3P + fidx);
    ushort8 a3h = *(const ushort8*)(A3P + fidx + 8);
    int row = m0 + w * 16 + (lane >> 4) * 4 + r;
    long roff = ((long)b << 16) + (long)row * 256 + (lane & 15);
#pragma unroll
    for (int j = 0; j < 8; ++j) {
      float A1 = acc[j][r] * inv;
      float A2 = bf2f(a2l[j]), A3 = bf2f(a3l[j]);
      float m = fmaxf(A1, fmaxf(A2, A3));
      float e1 = __expf(A1 - m), e2 = __expf(A2 - m), e3 = __expf(A3 - m);
      ATTN[roff + j * 16] = f2bf((A1 * e1 + A2 * e2 + A3 * e3) / (e1 + e2 + e3));
    }
#pragma unroll
    for (int j = 0; j < 8; ++j) {
      float A1 = acc[8 + j][r] * inv;
      float A2 = bf2f(a2h[j]), A3 = bf2f(a3h[j]);
      float m = fmaxf(A1, fmaxf(A2, A3));
      float e1 = __expf(A1 - m), e2 = __expf(A2 - m), e3 = __expf(A3 - m);
      ATTN[roff + (8 + j) * 16] = f2bf((A1 * e1 + A2 * e2 + A3 * e3) / (e1 + e2 + e3));
    }
  }
}

// ------- 8-wave TALL(256x128) NT GEMM, 3-stage pipeline, counted vmcnt (R13) --------
template <int F32OUT, int BIASMODE>
__global__ void __launch_bounds__(512) gemm8(
    const unsigned short* __restrict__ A, const unsigned short* __restrict__ B,
    void* __restrict__ OutV, const float* __restrict__ bias,
    int lda, int ldb, int K, long astr, long bstr, long ostr, int ldo) {
  extern __shared__ char smem[];  // per buf 48K: A [256][64]sw + B [128][64]sw
  const int t = threadIdx.x, lane = t & 63, wid = t >> 6;
  const int wmb = (wid >> 1) * 64, wnb = (wid & 1) * 64;
  const int m0 = blockIdx.y * 256, n0 = blockIdx.x * 128;
  const int bz = blockIdx.z;
  const unsigned short* Ab = A + (long)bz * astr + (long)m0 * lda;
  const unsigned short* Bb = B + (long)bz * bstr + (long)n0 * ldb;
  const int srow = t >> 3, ssl = t & 7;

  auto stage = [&](int buf, int k0) {  // 6 loads/thread
    char* s = smem + buf * 49152;
#pragma unroll
    for (int i = 0; i < 4; ++i) {
      int row = i * 64 + srow;
      gl2lds16(Ab + (long)row * lda + k0 + (ssl ^ (row & 7)) * 8, s + i * 8192 + t * 16);
    }
#pragma unroll
    for (int i = 0; i < 2; ++i) {
      int row = i * 64 + srow;
      gl2lds16(Bb + (long)row * ldb + k0 + (ssl ^ (row & 7)) * 8,
               s + 32768 + i * 8192 + t * 16);
    }
  };

  f32x4 acc[4][4] = {};
  const int nst = K >> 6;
  stage(0, 0);
  stage(1, 64);  // K>=256 in all uses
  for (int j = 0; j < nst; ++j) {
    if (j + 1 < nst) asm volatile("s_waitcnt vmcnt(6)" ::: "memory");
    else             asm volatile("s_waitcnt vmcnt(0)" ::: "memory");
    __builtin_amdgcn_s_barrier();
    if (j + 2 < nst) stage((j + 2) % 3, (j + 2) * 64);
    const char* s = smem + (j % 3) * 49152;
#pragma unroll
    for (int kk = 0; kk < 2; ++kk) {
      const int slot = kk * 4 + (lane >> 4);
      bf16x8 af[4], bfr[4];
#pragma unroll
      for (int mi = 0; mi < 4; ++mi) {
        int row = wmb + mi * 16 + (lane & 15);
        af[mi] = *(const bf16x8*)(s + row * 128 + 16 * (slot ^ (row & 7)));
      }
#pragma unroll
      for (int ni = 0; ni < 4; ++ni) {
        int row = wnb + ni * 16 + (lane & 15);
        bfr[ni] = *(const bf16x8*)(s + 32768 + row * 128 + 16 * (slot ^ (row & 7)));
      }
#pragma unroll
      for (int mi = 0; mi < 4; ++mi)
#pragma unroll
        for (int ni = 0; ni < 4; ++ni)
          acc[mi][ni] = __builtin_amdgcn_mfma_f32_16x16x32_bf16(af[mi], bfr[ni], acc[mi][ni], 0, 0, 0);
    }
  }
#pragma unroll
  for (int mi = 0; mi < 4; ++mi) {
    int rowb = m0 + wmb + mi * 16 + (lane >> 4) * 4;
    float rb[4];
#pragma unroll
    for (int r = 0; r < 4; ++r) rb[r] = (BIASMODE == 2) ? bias[rowb + r] : 0.0f;
#pragma unroll
    for (int ni = 0; ni < 4; ++ni) {
      int col = n0 + wnb + ni * 16 + (lane & 15);
#pragma unroll
      for (int r = 0; r < 4; ++r) {
        float v = acc[mi][ni][r] + rb[r];
        if constexpr (F32OUT)
          ((float*)OutV)[(long)bz * ostr + (long)(rowb + r) * ldo + col] = v;
        else
          ((unsigned short*)OutV)[(long)bz * ostr + (long)(rowb + r) * ldo + col] = f2bf(v);
      }
    }
  }
}

// ------------------------------------------------------------------------------------
extern "C" void kernel_launch(void* const* d_in, const int* in_sizes, int n_in,
                              void* d_out, int out_size, void* d_ws, size_t ws_size,
                              hipStream_t stream) {
  (void)in_sizes; (void)n_in; (void)out_size; (void)ws_size;
  const float* x   = (const float*)d_in[0];
  const float* wq1 = (const float*)d_in[1];
  const float* bq1 = (const float*)d_in[2];
  const float* wk1 = (const float*)d_in[3];
  const float* bk1 = (const float*)d_in[4];
  const float* wq2 = (const float*)d_in[5];
  const float* bq2 = (const float*)d_in[6];
  const float* wk2 = (const float*)d_in[7];
  const float* bk2 = (const float*)d_in[8];
  const float* wq3 = (const float*)d_in[9];
  const float* bq3 = (const float*)d_in[10];
  const float* wk3 = (const float*)d_in[11];
  const float* bk3 = (const float*)d_in[12];
  const float* wv  = (const float*)d_in[13];
  const float* bv  = (const float*)d_in[14];
  const float* wo  = (const float*)d_in[15];
  const float* bo  = (const float*)d_in[16];
  char* ws = (char*)d_ws;

  // workspace layout (bytes), peak ~94.4 MB
  unsigned short* XT   = (unsigned short*)(ws + 0);         // [64][256][512] 16.8MB
  unsigned short* WQK1 = (unsigned short*)(ws + 16777216);  // [256][512]
  unsigned short* WQK2 = (unsigned short*)(ws + 17039360);  // [256][256]
  unsigned short* WQK3 = (unsigned short*)(ws + 17170432);  // [256][128]
  unsigned short* WOT  = (unsigned short*)(ws + 17235968);  // [512][512] wo^T
  unsigned short* WVNT = (unsigned short*)(ws + 17760256);  // [512][512] wv row-major
  unsigned short* WVOT = (unsigned short*)(ws + 18284544);  // [512][512] (wv@wo)^T
  float*          BVO  = (float*)(ws + 18808832);           // [512] bv@wo
  unsigned short* QK1  = (unsigned short*)(ws + 18876416);  // [64][256][256]
  unsigned short* QK2  = (unsigned short*)(ws + 27265024);  // [128][256][256]
  unsigned short* QK3  = (unsigned short*)(ws + 44042240);  // [256][256][256]
  unsigned short* A2P  = (unsigned short*)(ws + 77596672);  // fragment layout
  unsigned short* A3P  = (unsigned short*)(ws + 85985280);  // fragment layout
  unsigned short* ATTN = (unsigned short*)(ws + 44042240);  // over dead QK3
  unsigned short* XVT  = (unsigned short*)(ws + 18876416);  // over dead QK1/QK2

  tcast_all<<<dim3(2296), dim3(256), 0, stream>>>(
      x, wq1, wk1, wq2, wk2, wq3, wk3, wv, wo,
      XT, WQK1, WQK2, WQK3, WVNT, WOT);

  proj_all8<<<dim3(1, 1, 468), dim3(512), 131072, stream>>>(
      XT, WQK1, WQK2, WQK3, WOT, WVNT, WVOT, BVO, bv,
      QK1, QK2, QK3, bq1, bk1, bq2, bk2, bq3, bk3);

  scores_mean<<<dim3(512), dim3(256), 0, stream>>>(QK2, QK3, A2P, A3P);
  scores1_gate<<<dim3(256), dim3(256), 0, stream>>>(QK1, A2P, A3P, ATTN);

  // XVT[b][p][d] = sum_s WVOT[p][s]*XT[b][d][s] + BVO[p]   (row-bias)
  gemm8<0, 2><<<dim3(2, 2, 64), dim3(512), 147456, stream>>>(
      WVOT, XT, XVT, BVO, 512, 512, 512, 0, 131072, 131072, 256);
  // out[b][p][c] = sum_d XVT[b][p][d]*ATTN[b][c][d] + bo[p] (row-bias, fp32)
  gemm8<1, 2><<<dim3(2, 2, 64), dim3(512), 147456, stream>>>(
      XVT, ATTN, d_out, bo, 256, 256, 256, 131072, 65536, 131072, 256);
}